// Round 4
// baseline (476.186 us; speedup 1.0000x reference)
//
#include <hip/hip_runtime.h>
#include <math.h>

#define BATCH   4
#define LSEQ    2048
#define DMODEL  1024
#define DSTATE  128
#define HEADDIM 64
#define DINNER  2048
#define NHEADS  32
#define CONVCH  2304
#define DINPROJ 4384
#define NPAD    4608
#define CHUNKL  128
#define NCHUNK  16
#define ROWS    (BATCH*LSEQ)

// ---------------- workspace layout (BYTE offsets) ----------------
#define B_Z     ((size_t)0)                              // ROWS*DINNER bf16
#define B_XBC   (B_Z   + (size_t)ROWS*DINNER*2)          // ROWS*CONVCH bf16; S aliases first 33.55MB; Wout bf16 aliases tail 4.19MB
#define B_DT    (B_XBC + (size_t)ROWS*CONVCH*2)          // ROWS*NHEADS fp32
#define B_XS    (B_DT  + (size_t)ROWS*NHEADS*4)          // ROWS*DINNER bf16
#define B_BC    (B_XS  + (size_t)ROWS*DINNER*2)          // ROWS*256 bf16
#define B_Y     (B_BC  + (size_t)ROWS*256*2)             // ROWS*DINNER bf16; h bf16 aliases [0,16.8MB); Win bf16 aliases [16.8MB,26.2MB)
#define B_ASUM  (B_Y   + (size_t)ROWS*DINNER*2)          // BATCH*NCHUNK*NHEADS fp32
#define B_END   (B_ASUM + (size_t)BATCH*NCHUNK*NHEADS*4) // ~137 MB total

typedef __attribute__((ext_vector_type(8))) short bf16x8;
typedef __attribute__((ext_vector_type(4))) float f32x4;

__device__ __forceinline__ float b2f(ushort u) {
  union { uint32_t i; float f; } v; v.i = ((uint32_t)u) << 16; return v.f;
}
__device__ __forceinline__ ushort f2b(float f) {
  union { float f; uint32_t i; } v; v.f = f;
  uint32_t r = (v.i + 0x7FFFu + ((v.i >> 16) & 1u)) >> 16;
  return (ushort)r;
}

__device__ __forceinline__ void async_ld16(const void* g, void* l) {
  __builtin_amdgcn_global_load_lds(
      (const __attribute__((address_space(1))) unsigned int*)g,
      (__attribute__((address_space(3))) unsigned int*)l, 16, 0, 0);
}

#define VMG(n) asm volatile("s_waitcnt vmcnt(" #n ")" ::: "memory")

// ======================================================================
// inproj 256x256 4-quadrant-phase core.
// Per phase: stage-issue(future half) -> counted VMG -> s_barrier (makes
// ALL waves' DMAs visible: vmcnt is per-wave, staging is cooperative!)
// -> ds_read frags -> MFMA -> s_barrier (reads done before overwrites).
// Half-tile ledger (prologue = insts 1..12; tile-t halves land at
// positions 8t+1..8t+8): p1 VMG(10) covers (t,Alo)+(t,Blo); p2 VMG(10)
// covers (t,Bhi); p3 VMG(10) covers (t,Ahi); p4 reuses p2's gate.
// vmcnt never drains to 0 in the main loop.
// ======================================================================

template<int K>
__device__ __forceinline__ void stage_half(const ushort* __restrict__ M,
    int row0, int k0, int tid, ushort* dst)
{
  #pragma unroll
  for (int it = 0; it < 2; it++) {
    int s = it*512 + tid;            // 0..1023
    int rl = s >> 3;                 // 0..127 (row within half; row%8 preserved)
    int g = (s & 7) ^ (rl & 7);
    async_ld16(M + (size_t)(row0 + rl)*K + k0 + g*8, dst + (size_t)s*8);
  }
}

template<int QM, int QN, bool RDA>
__device__ __forceinline__ void qphase(const ushort* __restrict__ bA,
    const ushort* __restrict__ bB, int wq, int wn, int rl, int q,
    bf16x8 (&af)[2][4], bf16x8 (&bfr)[2][2], f32x4 (&acc)[2][2][4][2])
{
  // BAR1: every wave has passed its own vmcnt gate -> the cooperatively
  // staged halves are fully in LDS before ANY wave's ds_read.
  __builtin_amdgcn_s_barrier();
  __builtin_amdgcn_sched_barrier(0);     // pin reads after the barrier
  if (RDA) {
    #pragma unroll
    for (int kh = 0; kh < 2; kh++)
      #pragma unroll
      for (int ii = 0; ii < 4; ii++) {
        int row = QM*128 + wq*64 + ii*16 + rl;
        af[kh][ii] = *(const bf16x8*)&bA[(size_t)(row*8 + ((kh*4 + q) ^ (row & 7)))*8];
      }
  }
  #pragma unroll
  for (int kh = 0; kh < 2; kh++)
    #pragma unroll
    for (int jj = 0; jj < 2; jj++) {
      int row = QN*128 + wn*32 + jj*16 + rl;
      bfr[kh][jj] = *(const bf16x8*)&bB[(size_t)(row*8 + ((kh*4 + q) ^ (row & 7)))*8];
    }
  __builtin_amdgcn_s_setprio(1);
  #pragma unroll
  for (int kh = 0; kh < 2; kh++)
    #pragma unroll
    for (int ii = 0; ii < 4; ii++)
      #pragma unroll
      for (int jj = 0; jj < 2; jj++)
        acc[QM][QN][ii][jj] = __builtin_amdgcn_mfma_f32_16x16x32_bf16(
            af[kh][ii], bfr[kh][jj], acc[QM][QN][ii][jj], 0, 0, 0);
  __builtin_amdgcn_s_setprio(0);
  __builtin_amdgcn_sched_barrier(0);
  // BAR2: all waves' LDS reads consumed before the next phase's
  // overwriting stage can be issued by any wave.
  __builtin_amdgcn_s_barrier();
}

// ---------------- 256x128 outproj helpers (round-2, unchanged) ----------------
template<int K>
__device__ __forceinline__ void stage_tile(const ushort* __restrict__ A,
    const ushort* __restrict__ W, int m0, int n0, int tid, int t,
    ushort* lA, ushort* lB)
{
  const int k0 = t * 64;
  #pragma unroll
  for (int it = 0; it < 4; it++) {          // A: 256 rows x 8 granules
    int s = it*512 + tid;
    int row = s >> 3;
    int g = (s & 7) ^ (row & 7);
    async_ld16(A + (size_t)(m0 + row)*K + k0 + g*8, lA + (size_t)s*8);
  }
  #pragma unroll
  for (int it = 0; it < 2; it++) {          // B: 128 rows x 8 granules
    int s = it*512 + tid;
    int row = s >> 3;
    int g = (s & 7) ^ (row & 7);
    async_ld16(W + (size_t)(n0 + row)*K + k0 + g*8, lB + (size_t)s*8);
  }
}

__device__ __forceinline__ void compute_tile(const ushort* lA, const ushort* lB,
    int wr, int wc, int rl, int q, f32x4 acc[4][4])
{
  #pragma unroll
  for (int kh = 0; kh < 2; kh++) {
    bf16x8 af[4], bfr[4];
    #pragma unroll
    for (int i = 0; i < 4; i++) {
      int row = wr*64 + i*16 + rl;
      af[i] = *(const bf16x8*)&lA[(size_t)(row*8 + ((kh*4 + q) ^ (row & 7)))*8];
    }
    #pragma unroll
    for (int j = 0; j < 4; j++) {
      int row = wc*64 + j*16 + rl;
      bfr[j] = *(const bf16x8*)&lB[(size_t)(row*8 + ((kh*4 + q) ^ (row & 7)))*8];
    }
    #pragma unroll
    for (int i = 0; i < 4; i++)
      #pragma unroll
      for (int j = 0; j < 4; j++)
        acc[i][j] = __builtin_amdgcn_mfma_f32_16x16x32_bf16(af[i], bfr[j], acc[i][j], 0, 0, 0);
  }
}

// ---------------- weight fp32 -> bf16 converters ----------------
__global__ __launch_bounds__(256) void convert_win_kernel(const float* __restrict__ W,
                                                          ushort* __restrict__ Wb)
{
  size_t i = (size_t)blockIdx.x*256 + threadIdx.x;
  Wb[i] = (i < (size_t)DINPROJ*DMODEL) ? f2b(W[i]) : (ushort)0;
}

__global__ __launch_bounds__(256) void convert_wout_kernel(const float* __restrict__ W,
                                                           ushort* __restrict__ Wb)
{
  size_t i = (size_t)blockIdx.x*256 + threadIdx.x;
  Wb[i] = f2b(W[i]);
}

// ---------------- LayerNorm -> h (bf16) ----------------
__global__ __launch_bounds__(256) void ln_kernel(const float* __restrict__ x,
    const float* __restrict__ w, const float* __restrict__ bias, ushort* __restrict__ h)
{
  const int row = blockIdx.x;
  const int t = threadIdx.x;
  const float* xr = x + (size_t)row * DMODEL;
  float v[4];
  float s = 0.f;
  #pragma unroll
  for (int i = 0; i < 4; i++) { v[i] = xr[t + i*256]; s += v[i]; }
  __shared__ float red[4];
  #pragma unroll
  for (int o = 32; o > 0; o >>= 1) s += __shfl_down(s, o, 64);
  if ((t & 63) == 0) red[t >> 6] = s;
  __syncthreads();
  float mean = (red[0]+red[1]+red[2]+red[3]) * (1.f/DMODEL);
  float vs = 0.f;
  #pragma unroll
  for (int i = 0; i < 4; i++) { float d = v[i]-mean; vs += d*d; }
  #pragma unroll
  for (int o = 32; o > 0; o >>= 1) vs += __shfl_down(vs, o, 64);
  __syncthreads();
  if ((t & 63) == 0) red[t >> 6] = vs;
  __syncthreads();
  float rstd = rsqrtf((red[0]+red[1]+red[2]+red[3]) * (1.f/DMODEL) + 1e-5f);
  ushort* hr = h + (size_t)row * DMODEL;
  #pragma unroll
  for (int i = 0; i < 4; i++) {
    int c = t + i*256;
    hr[c] = f2b((v[i]-mean)*rstd*w[c] + bias[c]);
  }
}

// ---------------- in_proj GEMM: 256x256, quadrant-phase schedule ----------------
// grid 576 (1-D): xcd = bid&7 owns m-blocks [4*xcd, 4*xcd+4), n-fastest within.
__global__ __launch_bounds__(512, 1) void gemm_inproj_8ph(const ushort* __restrict__ A,
    const ushort* __restrict__ W, ushort* __restrict__ z, ushort* __restrict__ xbc,
    float* __restrict__ dtr, const float* __restrict__ dtb)
{
  __shared__ ushort smem[65536];            // 128KB: buf d at d*32768 (A 16384, B 16384)
  const int tid = threadIdx.x;
  const int lane = tid & 63;
  const int w = tid >> 6;
  const int wq = w >> 2;                    // 0..1 (M within quadrant)
  const int wn = w & 3;                     // 0..3 (N within quadrant)
  const int rl = lane & 15;
  const int q  = lane >> 4;

  const int orig = blockIdx.x;              // [0,576)
  const int xcd  = orig & 7;
  const int jj_  = orig >> 3;               // [0,72)
  const int m0 = (xcd*4 + jj_/18) * 256;    // A panel pinned per XCD
  const int n0 = (jj_ % 18) * 256;          // n-fastest

  f32x4 acc[2][2][4][2];
  #pragma unroll
  for (int a = 0; a < 2; a++)
    #pragma unroll
    for (int b = 0; b < 2; b++)
      #pragma unroll
      for (int c = 0; c < 4; c++)
        #pragma unroll
        for (int d = 0; d < 2; d++) acc[a][b][c][d] = (f32x4)(0.f);

  bf16x8 af[2][4], bfr[2][2];
  constexpr int NT = DMODEL / 64;           // 16 K-tiles

  // prologue: issue (0,Alo),(0,Blo),(0,Bhi),(0,Ahi),(1,Alo),(1,Blo)  [12 insts]
  {
    ushort* A0 = smem;            ushort* B0 = smem + 16384;
    ushort* A1 = smem + 32768;    ushort* B1 = A1 + 16384;
    stage_half<DMODEL>(A, m0+0,   0,  tid, A0);
    stage_half<DMODEL>(W, n0+0,   0,  tid, B0);
    stage_half<DMODEL>(W, n0+128, 0,  tid, B0 + 8192);
    stage_half<DMODEL>(A, m0+128, 0,  tid, A0 + 8192);
    stage_half<DMODEL>(A, m0+0,   64, tid, A1);
    stage_half<DMODEL>(W, n0+0,   64, tid, B1);
  }

  // main loop: t = 0..NT-3, all stages present, uniform vmcnt(10) gates
  for (int t = 0; t < NT-2; t++) {
    const int d = t & 1;
    const ushort* bA = smem + d*32768;
    const ushort* bB = bA + 16384;
    ushort* nA = smem + (d^1)*32768;        // buf for tile t+1
    ushort* nB = nA + 16384;
    ushort* sA = smem + d*32768;            // buf for tile t+2 (same as t)
    ushort* sB = sA + 16384;
    // p1: stage (t+1,Bhi); compute Q(0,0)
    stage_half<DMODEL>(W, n0+128, (t+1)*64, tid, nB + 8192);
    VMG(10);
    qphase<0,0,true >(bA, bB, wq, wn, rl, q, af, bfr, acc);
    // p2: stage (t+1,Ahi); compute Q(0,1)
    stage_half<DMODEL>(A, m0+128, (t+1)*64, tid, nA + 8192);
    VMG(10);
    qphase<0,1,false>(bA, bB, wq, wn, rl, q, af, bfr, acc);
    // p3: stage (t+2,Alo); compute Q(1,0)
    stage_half<DMODEL>(A, m0+0, (t+2)*64, tid, sA);
    VMG(10);
    qphase<1,0,true >(bA, bB, wq, wn, rl, q, af, bfr, acc);
    // p4: stage (t+2,Blo); compute Q(1,1) (B-hi gated at p2; af in regs)
    stage_half<DMODEL>(W, n0+0, (t+2)*64, tid, sB);
    qphase<1,1,false>(bA, bB, wq, wn, rl, q, af, bfr, acc);
  }
  // peeled t = NT-2: p1/p2 stage (NT-1)'s Bhi/Ahi; no t+2 stages
  {
    const int t = NT-2;
    const int d = t & 1;
    const ushort* bA = smem + d*32768;
    const ushort* bB = bA + 16384;
    ushort* nA = smem + (d^1)*32768;
    ushort* nB = nA + 16384;
    stage_half<DMODEL>(W, n0+128, (t+1)*64, tid, nB + 8192);
    VMG(10);
    qphase<0,0,true >(bA, bB, wq, wn, rl, q, af, bfr, acc);
    stage_half<DMODEL>(A, m0+128, (t+1)*64, tid, nA + 8192);
    VMG(10);
    qphase<0,1,false>(bA, bB, wq, wn, rl, q, af, bfr, acc);
    VMG(8);
    qphase<1,0,true >(bA, bB, wq, wn, rl, q, af, bfr, acc);
    qphase<1,1,false>(bA, bB, wq, wn, rl, q, af, bfr, acc);
  }
  // peeled t = NT-1: no stages; draining gates
  {
    const int t = NT-1;
    const int d = t & 1;
    const ushort* bA = smem + d*32768;
    const ushort* bB = bA + 16384;
    VMG(4);
    qphase<0,0,true >(bA, bB, wq, wn, rl, q, af, bfr, acc);
    VMG(2);
    qphase<0,1,false>(bA, bB, wq, wn, rl, q, af, bfr, acc);
    VMG(0);
    qphase<1,0,true >(bA, bB, wq, wn, rl, q, af, bfr, acc);
    qphase<1,1,false>(bA, bB, wq, wn, rl, q, af, bfr, acc);
  }

  const int colL = lane & 15;
  const int rowQ = (lane >> 4) * 4;
  if (n0 < DINNER + CONVCH) {
    // swizzled bf16 restage of the 256x256 tile (128KB), then coalesced 16B stores
    #pragma unroll
    for (int qm = 0; qm < 2; qm++)
      #pragma unroll
      for (int qn = 0; qn < 2; qn++)
        #pragma unroll
        for (int ii = 0; ii < 4; ii++)
          #pragma unroll
          for (int jj = 0; jj < 2; jj++) {
            int col = qn*128 + wn*32 + jj*16 + colL;
            int g = col >> 3;
            #pragma unroll
            for (int r = 0; r < 4; r++) {
              int row = qm*128 + wq*64 + ii*16 + rowQ + r;
              int p = (g & 24) | ((g ^ row) & 7);
              smem[row*256 + p*8 + (col & 7)] = f2b(acc[qm][qn][ii][jj][r]);
            }
          }
    __syncthreads();
    ushort* outp; int coff, ncols;
    if (n0 < DINNER) { outp = z;   coff = n0;          ncols = DINNER; }
    else             { outp = xbc; coff = n0 - DINNER; ncols = CONVCH; }
    #pragma unroll
    for (int it = 0; it < 16; it++) {
      int idx = tid + it*512;               // 256 rows x 32 granules = 8192
      int row = idx >> 5, g = idx & 31;
      int p = (g & 24) | ((g ^ row) & 7);
      *(uint4*)(outp + (size_t)(m0 + row)*ncols + coff + g*8) =
          *(const uint4*)&smem[row*256 + p*8];
    }
  } else {
    // dt tile (n0 == 4352): only local cols [0,32) real (qn=0, wn=0)
    if (wn == 0) {
      #pragma unroll
      for (int qm = 0; qm < 2; qm++)
        #pragma unroll
        for (int ii = 0; ii < 4; ii++)
          #pragma unroll
          for (int jj = 0; jj < 2; jj++) {
            int lc = jj*16 + colL;          // < 32
            float bb = dtb[lc];
            #pragma unroll
            for (int r = 0; r < 4; r++) {
              float v = acc[qm][0][ii][jj][r] + bb;
              v = (v > 20.f) ? v : log1pf(expf(v));
              dtr[(size_t)(m0 + qm*128 + wq*64 + ii*16 + rowQ + r)*NHEADS + lc] = v;
            }
          }
    }
  }
}

// ---------------- out_proj GEMM: 256x128, counted vmcnt, XCD m-partition ----------------
__global__ __launch_bounds__(512, 1) void gemm_outproj_big(const ushort* __restrict__ A,
    const ushort* __restrict__ W, const float* __restrict__ x, float* __restrict__ out)
{
  __shared__ ushort smem[49152];            // 96KB
  ushort* lA0 = smem;                       // 2 x 16384
  ushort* lB0 = smem + 32768;               // 2 x 8192
  float* fbuf = (float*)smem;               // epilogue: 128x128 f32 = 64KB
  const int tid = threadIdx.x;
  const int lane = tid & 63;
  const int w = tid >> 6;
  const int wr = w >> 1;                    // 0..3 (M)
  const int wc = w & 1;                     // 0..1 (N)
  const int rl = lane & 15;
  const int q  = lane >> 4;

  const int orig = blockIdx.x;              // [0,256)
  const int xcd  = orig & 7;
  const int jj   = orig >> 3;               // [0,32)
  const int m0 = (xcd*4 + (jj >> 3)) * 256;
  const int n0 = (jj & 7) * 128;

  f32x4 acc[4][4];
  #pragma unroll
  for (int i = 0; i < 4; i++)
    #pragma unroll
    for (int j = 0; j < 4; j++) acc[i][j] = (f32x4)(0.f);

  constexpr int NT = DINNER / 64;           // 32 K-tiles
  stage_tile<DINNER>(A, W, m0, n0, tid, 0, lA0, lB0);
  for (int t = 0; t < NT; t++) {
    const ushort* cA = lA0 + (size_t)(t & 1) * 16384;
    const ushort* cB = lB0 + (size_t)(t & 1) * 8192;
    if (t + 1 < NT) {
      stage_tile<DINNER>(A, W, m0, n0, tid, t + 1,
                         lA0 + (size_t)((t+1) & 1) * 16384,
                         lB0 + (size_t)((t+1) & 1) * 8192);
      asm volatile("s_waitcnt vmcnt(6)" ::: "memory");   // t's 6 loads done; t+1's fly
    } else {
      asm volatile("s_waitcnt vmcnt(0)" ::: "memory");
    }
    __builtin_amdgcn_s_barrier();
    __builtin_amdgcn_sched_barrier(0);
    __builtin_amdgcn_s_setprio(1);
    compute_tile(cA, cB, wr, wc, rl, q, acc);
    __builtin_amdgcn_s_setprio(0);
    __builtin_amdgcn_sched_barrier(0);
    __builtin_amdgcn_s_barrier();
  }

  const int colL = lane & 15;
  const int rowQ = (lane >> 4) * 4;
  // fp32 restage in two 128-row halves (64KB each), fused residual add
  #pragma unroll
  for (int h = 0; h < 2; h++) {
    __syncthreads();
    if ((wr >> 1) == h) {                   // waves wr in {2h, 2h+1}
      #pragma unroll
      for (int i = 0; i < 4; i++)
        #pragma unroll
        for (int j = 0; j < 4; j++) {
          int col = wc*64 + j*16 + colL;
          int g = col >> 2;
          #pragma unroll
          for (int r = 0; r < 4; r++) {
            int row = (wr & 1)*64 + i*16 + rowQ + r;
            fbuf[row*128 + ((g ^ (row & 7)) << 2) + (col & 3)] = acc[i][j][r];
          }
        }
    }
    __syncthreads();
    #pragma unroll
    for (int it = 0; it < 8; it++) {
      int idx = tid + it*512;               // 128 rows x 32 float4 = 4096
      int row = idx >> 5, c4 = idx & 31;
      int gm = m0 + h*128 + row;
      float4 xv = *(const float4*)(x + (size_t)gm*DMODEL + n0 + c4*4);
      float4 vv = *(const float4*)&fbuf[row*128 + ((c4 ^ (row & 7)) << 2)];
      vv.x += xv.x; vv.y += xv.y; vv.z += xv.z; vv.w += xv.w;
      *(float4*)(out + (size_t)gm*DMODEL + n0 + c4*4) = vv;
    }
  }
}

// ---------------- causal conv4 + SiLU, LDS row-tiled ----------------
__global__ __launch_bounds__(256) void conv_tiled(const ushort* __restrict__ xbc,
    const float* __restrict__ cw, const float* __restrict__ cb,
    ushort* __restrict__ xs, ushort* __restrict__ bcb)
{
  __shared__ ushort tile[35*256];
  const int tid = threadIdx.x;
  const int ch0 = blockIdx.x * 256;
  const int row0 = blockIdx.y * 32;
  const int l0 = row0 & (LSEQ-1);
  for (int idx = tid; idx < 35*32; idx += 256) {
    int r = idx >> 5, c16 = idx & 31;
    uint4 v = make_uint4(0,0,0,0);
    if (l0 + r - 3 >= 0)
      v = *(const uint4*)(xbc + (size_t)(row0 + r - 3)*CONVCH + ch0 + c16*8);
    *(uint4*)&tile[r*256 + c16*8] = v;
  }
  __syncthreads();
  const int ch = ch0 + tid;
  const float w0 = cw[ch*4+0], w1 = cw[ch*4+1], w2 = cw[ch*4+2], w3 = cw[ch*4+3];
  const float bias = cb[ch];
  const bool isX = (ch0 < DINNER);
  #pragma unroll 4
  for (int r = 0; r < 32; r++) {
    float acc = bias;
    acc = fmaf(b2f(tile[(r+0)*256 + tid]), w0, acc);
    acc = fmaf(b2f(tile[(r+1)*256 + tid]), w1, acc);
    acc = fmaf(b2f(tile[(r+2)*256 + tid]), w2, acc);
    acc = fmaf(b2f(tile[(r+3)*256 + tid]), w3, acc);
    float v = acc / (1.f + expf(-acc));
    if (isX) xs[(size_t)(row0 + r)*DINNER + ch] = f2b(v);
    else     bcb[(size_t)(row0 + r)*256 + (ch - DINNER)] = f2b(v);
  }
}

// ---------------- per-chunk states via MFMA: S[p][n] = sum_l Xw[l][p]*B[l][n] ----------------
__global__ __launch_bounds__(256) void states_mfma(
    const ushort* __restrict__ xs, const ushort* __restrict__ bcb, const float* __restrict__ dt,
    const float* __restrict__ A_log, ushort* __restrict__ S, float* __restrict__ asum)
{
  constexpr int LDP = 136;
  __shared__ ushort lBT[128*LDP];   // B^T[n][l]
  __shared__ ushort lXT[64*LDP];    // Xw^T[p][l]; reused for S restage
  __shared__ float dts[CHUNKL], acs[CHUNKL];
  __shared__ float wtot;
  const int hh = blockIdx.x, c = blockIdx.y, b = blockIdx.z;
  const int tid = threadIdx.x;
  const int lane = tid & 63;
  const int w = tid >> 6;
  const int rbase = b*LSEQ + c*CHUNKL;
  const size_t sbase = (size_t)((b*NCHUNK + c)*NHEADS + hh) * 8192;

  float pre = 0.f;
  if (tid < 128) {
    float myv = dt[(size_t)(rbase + tid)*NHEADS + hh];
    dts[tid] = myv;
    pre = myv;
    #pragma unroll
    for (int o = 1; o < 64; o <<= 1) {
      float u = __shfl_up(pre, o, 64);
      if ((tid & 63) >= o) pre += u;
    }
    if (tid == 63) wtot = pre;
  }
  #pragma unroll
  for (int it = 0; it < 8; it++) {
    int chunk = tid + it*256;
    int l = chunk >> 4, n8 = chunk & 15;
    ushort tmp[8];
    *(uint4*)tmp = *(const uint4*)(bcb + (size_t)(rbase + l)*256 + n8*8);
    #pragma unroll
    for (int u = 0; u < 8; u++) lBT[(n8*8+u)*LDP + l] = tmp[u];
  }
  __syncthreads();
  float alast_loc = 0.f;
  if (tid < 128) {
    float Aval = -expf(A_log[hh]);
    float a = (pre + ((tid >= 64) ? wtot : 0.f)) * Aval;
    acs[tid] = a;
    if (tid == 127) { asum[(b*NCHUNK + c)*NHEADS + hh] = a; }
  }
  __syncthreads();
  alast_loc = acs[CHUNKL-1];
  #pragma unroll
  for (int it = 0; it < 4; it++) {
    int chunk = tid + it*256;
    int l = chunk >> 3, p8 = (chunk & 7)*8;
    ushort tmp[8];
    *(uint4*)tmp = *(const uint4*)(xs + (size_t)(rbase + l)*DINNER + hh*HEADDIM + p8);
    float wl = dts[l] * expf(alast_loc - acs[l]);
    #pragma unroll
    for (int u = 0; u < 8; u++) lXT[(p8+u)*LDP + l] = f2b(b2f(tmp[u]) * wl);
  }
  __syncthreads();

  const int rl = lane & 15;
  const int kq = (lane >> 4) * 8;
  const int nb = w * 32;
  f32x4 acc[4][2];
  #pragma unroll
  for (int i = 0; i < 4; i++) { acc[i][0] = (f32x4)(0.f); acc[i][1] = (f32x4)(0.f); }
  #pragma unroll
  for (int k0 = 0; k0 < 128; k0 += 32) {
    bf16x8 af[4], bfr[2];
    #pragma unroll
    for (int i = 0; i < 4; i++) af[i]  = *(const bf16x8*)&lXT[(i*16 + rl)*LDP + k0 + kq];
    #pragma unroll
    for (int j = 0; j < 2; j++) bfr[j] = *(const bf16x8*)&lBT[(nb + j*16 + rl)*LDP + k0 + kq];
    #pragma unroll
    for (int i = 0; i < 4; i++)
      #pragma unroll
      for (int j = 0; j < 2; j++)
        acc[i][j] = __builtin_amdgcn_mfma_f32_16x16x32_bf16(af[i], bfr[j], acc[i][j], 0, 0, 0);
  }
  __syncthreads();
  const int colL = lane & 15;
  const int rowQ = (lane >> 4) * 4;
  #pragma unroll
  for (int i = 0; i < 4; i++)
    #pragma unroll
    for (int j = 0; j < 2; j++)
      #pragma unroll
      for (int r = 0; r < 4; r++)
        lXT[(i*16 + rowQ + r)*LDP + nb + j*16 + colL] = f2b(acc[i][j][r]);
  __syncthreads();
  #pragma unroll
  for (int it = 0; it < 4; it++) {
    int idx = tid + it*256;
    int row = idx >> 4, c8 = idx & 15;
    *(uint4*)(S + sbase + row*128 + c8*8) = *(const uint4*)&lXT[row*LDP + c8*8];
  }
}

// ---------------- inter-chunk scan, split 4x over state slices ----------------
__global__ __launch_bounds__(256) void scan_kernel(ushort* __restrict__ S, const float* __restrict__ asum)
{
  const int hh = blockIdx.x, sl = blockIdx.y, b = blockIdx.z;
  const int base0 = sl*2048 + threadIdx.x;
  float carry[8];
  #pragma unroll
  for (int i = 0; i < 8; i++) carry[i] = 0.f;
  for (int c = 0; c < NCHUNK; c++) {
    ushort* Sp = S + (size_t)((b*NCHUNK + c)*NHEADS + hh) * 8192;
    float dec = expf(asum[(b*NCHUNK + c)*NHEADS + hh]);
    #pragma unroll
    for (int i = 0; i < 8; i++) {
      int idx = base0 + i*256;
      float sv = b2f(Sp[idx]);
      Sp[idx] = f2b(carry[i]);
      carry[i] = fmaf(dec, carry[i], sv);
    }
  }
}

// ---------------- yssd MFMA v2: direct-global fragments for C/B/P; LDS only M + X^T ----------------
__global__ __launch_bounds__(256) void yssd_mfma(
    const ushort* __restrict__ xs, const ushort* __restrict__ bcb, const float* __restrict__ dt,
    const float* __restrict__ A_log, const float* __restrict__ Dvec,
    const ushort* __restrict__ S, ushort* __restrict__ y)
{
  constexpr int LDP = 136;
  __shared__ ushort lM [128*LDP];   // M[l][s]
  __shared__ ushort lXT[64*LDP];    // X^T[p][s]
  __shared__ float dts[CHUNKL], acs[CHUNKL];
  __shared__ float wtot;
  const int hh = blockIdx.x, c = blockIdx.y, b = blockIdx.z;
  const int tid = threadIdx.x;
  const int lane = tid & 63;
  const int w = tid >> 6;
  const int rbase = b*LSEQ + c*CHUNKL;
  const size_t sbase = (size_t)((b*NCHUNK + c)*NHEADS + hh) * 8192;
  const ushort* Bg = bcb + (size_t)rbase*256;        // B row s at Bg + s*256
  const ushort* Cg = Bg + 128;                       // C row l at Cg + l*256

  // stage X^T (transposing scatter) — the only global->LDS staging
  #pragma unroll
  for (int it = 0; it < 4; it++) {
    int chunk = tid + it*256;
    int s = chunk >> 3, p0 = (chunk & 7)*8;
    ushort tmp[8];
    *(uint4*)tmp = *(const uint4*)(xs + (size_t)(rbase + s)*DINNER + hh*HEADDIM + p0);
    #pragma unroll
    for (int u = 0; u < 8; u++) lXT[(p0+u)*LDP + s] = tmp[u];
  }
  // dt load + wave-parallel inclusive scan
  float pre = 0.f;
  if (tid < 128) {
    float myv = dt[(size_t)(rbase + tid)*NHEADS + hh];
    dts[tid] = myv;
    pre = myv;
    #pragma unroll
    for (int o = 1; o < 64; o <<= 1) {
      float u = __shfl_up(pre, o, 64);
      if ((tid & 63) >= o) pre += u;
    }
    if (tid == 63) wtot = pre;
  }
  __syncthreads();
  if (tid < 128) {
    float Aval = -expf(A_log[hh]);
    acs[tid] = (pre + ((tid >= 64) ? wtot : 0.f)) * Aval;
  }

  const int rl = lane & 15;
  const int kq = (lane >> 4) * 8;
  const int colL = lane & 15;
  const int rowQ = (lane >> 4) * 4;

  // ---- GEMM1: G[l][s] = sum_n C[l][n]*B[s][n], fragments direct from global
  const int wm = (w & 1) * 64;
  const int wn = (w >> 1) * 64;
  f32x4 G[4][4];
  #pragma unroll
  for (int i = 0; i < 4; i++)
    #pragma unroll
    for (int j = 0; j < 4; j++) G[i][j] = (f32x4)(0.f);
  #pragma unroll
  for (int k0 = 0; k0 < 128; k0 += 32) {
    bf16x8 af[4], bfr[4];
    #pragma unroll
    for (int i = 0; i < 4; i++) af[i]  = *(const bf16x8*)(Cg + (size_t)(wm + i*16 + rl)*256 + k0 + kq);
    #pragma unroll
    for (int j = 0; j < 4; j++) bfr[j] = *(const bf16x8*)(Bg + (size_t)(wn + j*16 + rl)*256 + k0 + kq);
    #pragma unroll
    for (int i = 0; i < 4; i++)
      #pragma unroll
      for (int j = 0; j < 4; j++)
        G[i][j] = __builtin_amdgcn_mfma_f32_16x16x32_bf16(af[i], bfr[j], G[i][j], 0, 0, 0);
  }
  __syncthreads();   // acs (written pre-GEMM1 by tid<128) visible to all; XT staged

  // ---- M[l][s] = (l>=s) ? G*exp(acs[l]-acs[s])*dt[s] : 0  -> lM
  #pragma unroll
  for (int j = 0; j < 4; j++) {
    int sIdx = wn + j*16 + colL;
    float as = acs[sIdx];
    float ds = dts[sIdx];
    #pragma unroll
    for (int i = 0; i < 4; i++) {
      #pragma unroll
      for (int r = 0; r < 4; r++) {
        int lIdx = wm + i*16 + rowQ + r;
        float m = (lIdx >= sIdx) ? G[i][j][r] * expf(acs[lIdx] - as) * ds : 0.f;
        lM[lIdx*LDP + sIdx] = f2b(m);
      }
    }
  }

  // ---- GEMM-off: Y[l][p] = sum_n C[l][n]*P[p][n], C and P direct from global
  const int om = w * 32;
  f32x4 Y[2][4];
  #pragma unroll
  for (int i = 0; i < 2; i++)
    #pragma unroll
    for (int j = 0; j < 4; j++) Y[i][j] = (f32x4)(0.f);
  #pragma unroll
  for (int k0 = 0; k0 < 128; k0 += 32) {
    bf16x8 a2[2], b2[4];
    #pragma unroll
    for (int i = 0; i < 2; i++) a2[i] = *(const bf16x8*)(Cg + (size_t)(om + i*16 + rl)*256 + k0 + kq);
    #pragma unroll
    for (int j = 0; j < 4; j++) b2[j] = *(const bf16x8*)(S + sbase + (size_t)(j*16 + rl)*128 + k0 + kq);
    #pragma unroll
    for (int i = 0; i < 2; i++)
      #pragma unroll
      for (int j = 0; j < 4; j++)
        Y[i][j] = __builtin_amdgcn_mfma_f32_16x16x32_bf16(a2[i], b2[j], Y[i][j], 0, 0, 0);
  }
  #pragma unroll
  for (int i = 0; i < 2; i++)
    #pragma unroll
    for (int r = 0; r < 4; r++) {
      float e = expf(acs[om + i*16 + rowQ + r]);
      #pragma unroll
      for (int j = 0; j < 4; j++) Y[i][j][r] *= e;
    }
  __syncthreads();   // lM writes visible

  // ---- GEMM-diag: Y[l][p] += sum_s M[l][s]*XT[p][s]
  #pragma unroll
  for (int k0 = 0; k0 < 128; k0 += 32) {
    bf16x8 a3[2], b3[4];
    #pragma unroll
    for (int i = 0; i < 2; i++) a3[i] = *(const bf16x8*)&lM[(om + i*16 + rl)*LDP + k0 + kq];
    #pragma unroll
    for (int j = 0; j < 4; j++) b3[j] = *(const bf16x8*)&lXT[(j*16 + rl)*LDP + k0 + kq];
    #pragma unroll
    for (int i = 0; i < 2; i++)
      #pragma unroll
      for (int j = 0; j < 4; j++)
        Y[i][j] = __builtin_amdgcn_mfma_f32_16x16x32_bf16(a3[i], b3[j], Y[i][j], 0, 0, 0);
  }

  // ---- epilogue: += D*xs, write bf16
  const float Dh = Dvec[hh];
  #pragma unroll
  for (int i = 0; i < 2; i++) {
    #pragma unroll
    for (int r = 0; r < 4; r++) {
      int lIdx = om + i*16 + rowQ + r;
      ushort* yrow = y + (size_t)(rbase + lIdx)*DINNER + hh*HEADDIM;
      #pragma unroll
      for (int j = 0; j < 4; j++) {
        int p = j*16 + colL;
        float val = Y[i][j][r] + Dh * b2f(lXT[p*LDP + lIdx]);
        yrow[p] = f2b(val);
      }
    }
  }
}

// ---------------- gated RMSNorm (in place on y, bf16) ----------------
__global__ __launch_bounds__(256) void rmsnorm_kernel(ushort* __restrict__ y,
    const ushort* __restrict__ z, const float* __restrict__ nw)
{
  const int row = blockIdx.x;
  const int t = threadIdx.x;
  ushort* yr = y + (size_t)row*DINNER;
  const ushort* zr = z + (size_t)row*DINNER;
  float v[8];
  float ss = 0.f;
  #pragma unroll
  for (int i = 0; i < 8; i++) {
    int c = t + i*256;
    float zz = b2f(zr[c]);
    float g = b2f(yr[c]) * (zz / (1.f + expf(-zz)));
    v[i] = g;
    ss += g*g;
  }
  #pragma unroll
  for (int o = 32; o > 0; o >>= 1) ss += __shfl_down(ss, o, 64);
  __shared__ float red[4];
  if ((t & 63) == 0) red[t >> 6] = ss;
  __syncthreads();
  float scale = rsqrtf((red[0]+red[1]+red[2]+red[3]) * (1.f/DINNER) + 1e-5f);
  #pragma unroll
  for (int i = 0; i < 8; i++) {
    int c = t + i*256;
    yr[c] = f2b(v[i]*scale*nw[c]);
  }
}

extern "C" void kernel_launch(void* const* d_in, const int* in_sizes, int n_in,
                              void* d_out, int out_size, void* d_ws, size_t ws_size,
                              hipStream_t stream)
{
  const float* x    = (const float*)d_in[0];
  const float* lnw  = (const float*)d_in[1];
  const float* lnb  = (const float*)d_in[2];
  const float* win  = (const float*)d_in[3];
  const float* cw   = (const float*)d_in[4];
  const float* cb   = (const float*)d_in[5];
  const float* dtb  = (const float*)d_in[6];
  const float* alog = (const float*)d_in[7];
  const float* dvec = (const float*)d_in[8];
  const float* nw   = (const float*)d_in[9];
  const float* wout = (const float*)d_in[10];
  float* out = (float*)d_out;
  char* ws = (char*)d_ws;
  (void)in_sizes; (void)n_in; (void)out_size;

  if (ws_size < B_END) return;  // workspace too small: fail cleanly, don't fault

  ushort* zb   = (ushort*)(ws + B_Z);
  ushort* xbcb = (ushort*)(ws + B_XBC);
  float*  dtr  = (float*) (ws + B_DT);
  ushort* xsb  = (ushort*)(ws + B_XS);
  ushort* bcb  = (ushort*)(ws + B_BC);
  ushort* yb   = (ushort*)(ws + B_Y);
  float*  asum = (float*) (ws + B_ASUM);
  ushort* Sb   = xbcb;                                        // aliases xbc (dead after conv)
  ushort* hb   = yb;                                          // aliases y[0 : 16.8MB]
  ushort* winB = (ushort*)(ws + B_Y + (size_t)ROWS*DMODEL*2); // aliases y[16.8MB : 26.2MB) (4608x1024 bf16 = 9.44MB)
  ushort* woutB= (ushort*)(ws + B_XBC + (size_t)BATCH*NCHUNK*NHEADS*HEADDIM*DSTATE*2); // XBC tail (4.19MB)

  hipLaunchKernelGGL(convert_win_kernel, dim3((NPAD*DMODEL)/256), dim3(256), 0, stream, win, winB);
  hipLaunchKernelGGL(ln_kernel, dim3(ROWS), dim3(256), 0, stream, x, lnw, lnb, hb);
  hipLaunchKernelGGL(gemm_inproj_8ph, dim3(576), dim3(512), 0, stream, hb, winB, zb, xbcb, dtr, dtb);
  hipLaunchKernelGGL(conv_tiled, dim3(9, ROWS/32), dim3(256), 0, stream, xbcb, cw, cb, xsb, bcb);
  hipLaunchKernelGGL(convert_wout_kernel, dim3((DMODEL*DINNER)/256), dim3(256), 0, stream, wout, woutB);
  hipLaunchKernelGGL(states_mfma, dim3(NHEADS, NCHUNK, BATCH), dim3(256), 0, stream,
                     xsb, bcb, dtr, alog, Sb, asum);
  hipLaunchKernelGGL(scan_kernel, dim3(NHEADS, 4, BATCH), dim3(256), 0, stream, Sb, asum);
  hipLaunchKernelGGL(yssd_mfma, dim3(NHEADS, NCHUNK, BATCH), dim3(256), 0, stream,
                     xsb, bcb, dtr, alog, dvec, Sb, yb);
  hipLaunchKernelGGL(rmsnorm_kernel, dim3(ROWS), dim3(256), 0, stream, yb, zb, nw);
  hipLaunchKernelGGL(gemm_outproj_big, dim3(256), dim3(512), 0, stream, yb, woutB, x, out);
}

// Round 5
// 468.667 us; speedup vs baseline: 1.0160x; 1.0160x over previous
//
#include <hip/hip_runtime.h>
#include <math.h>

#define BATCH   4
#define LSEQ    2048
#define DMODEL  1024
#define DSTATE  128
#define HEADDIM 64
#define DINNER  2048
#define NHEADS  32
#define CONVCH  2304
#define DINPROJ 4384
#define NPAD    4608
#define CHUNKL  128
#define NCHUNK  16
#define ROWS    (BATCH*LSEQ)

// ---------------- workspace layout (BYTE offsets) ----------------
#define B_Z     ((size_t)0)                              // ROWS*DINNER bf16
#define B_XBC   (B_Z   + (size_t)ROWS*DINNER*2)          // ROWS*CONVCH bf16; S aliases first 33.55MB; Wout bf16 aliases tail 4.19MB
#define B_DT    (B_XBC + (size_t)ROWS*CONVCH*2)          // ROWS*NHEADS fp32
#define B_XS    (B_DT  + (size_t)ROWS*NHEADS*4)          // ROWS*DINNER bf16
#define B_BC    (B_XS  + (size_t)ROWS*DINNER*2)          // ROWS*256 bf16
#define B_Y     (B_BC  + (size_t)ROWS*256*2)             // ROWS*DINNER bf16; h bf16 aliases [0,16.8MB); Win bf16 aliases [16.8MB,26.2MB)
#define B_ASUM  (B_Y   + (size_t)ROWS*DINNER*2)          // BATCH*NCHUNK*NHEADS fp32
#define B_END   (B_ASUM + (size_t)BATCH*NCHUNK*NHEADS*4) // ~137 MB total

typedef __attribute__((ext_vector_type(8))) short bf16x8;
typedef __attribute__((ext_vector_type(4))) float f32x4;

__device__ __forceinline__ float b2f(ushort u) {
  union { uint32_t i; float f; } v; v.i = ((uint32_t)u) << 16; return v.f;
}
__device__ __forceinline__ ushort f2b(float f) {
  union { float f; uint32_t i; } v; v.f = f;
  uint32_t r = (v.i + 0x7FFFu + ((v.i >> 16) & 1u)) >> 16;
  return (ushort)r;
}

__device__ __forceinline__ void async_ld16(const void* g, void* l) {
  __builtin_amdgcn_global_load_lds(
      (const __attribute__((address_space(1))) unsigned int*)g,
      (__attribute__((address_space(3))) unsigned int*)l, 16, 0, 0);
}

#define VMG(n) asm volatile("s_waitcnt vmcnt(" #n ")" ::: "memory")

// ======================================================================
// inproj 256x256 quadrant-phase core, m201-style derived waits.
// Per phase: {ds_read frags (current tile's buffer, already visible) ->
// stage 1 half-tile -> [VMG(4) at p4 only] -> barrier -> lgkmcnt(0)+
// sched_barrier -> setprio(1) 16 MFMA setprio(0) -> barrier}.
// ds_read latency overlaps the barrier wait (the round-4 port exposed it).
// Visibility: tile t's 8 stage-insts are gated by VMG(4) in tile t-1's p4
// BEFORE that phase's barriers -> buffer[t] visible for all of tile t.
// Overwrite safety: t+2's halves land in buf[t&1] only >=1 barrier after
// the overwritten half's reads completed (lgkmcnt(0) before that MFMA).
// ======================================================================

template<int K>
__device__ __forceinline__ void stage_half(const ushort* __restrict__ M,
    int row0, int k0, int tid, ushort* dst)
{
  #pragma unroll
  for (int it = 0; it < 2; it++) {
    int s = it*512 + tid;            // 0..1023
    int rl = s >> 3;                 // 0..127 (row within half; row%8 preserved)
    int g = (s & 7) ^ (rl & 7);
    async_ld16(M + (size_t)(row0 + rl)*K + k0 + g*8, dst + (size_t)s*8);
  }
}

template<int QM, int QN, bool RDA>
__device__ __forceinline__ void qreads(const ushort* __restrict__ bA,
    const ushort* __restrict__ bB, int wq, int wn, int rl, int q,
    bf16x8 (&af)[2][4], bf16x8 (&bfr)[2][2])
{
  if (RDA) {
    #pragma unroll
    for (int kh = 0; kh < 2; kh++)
      #pragma unroll
      for (int ii = 0; ii < 4; ii++) {
        int row = QM*128 + wq*64 + ii*16 + rl;
        af[kh][ii] = *(const bf16x8*)&bA[(size_t)(row*8 + ((kh*4 + q) ^ (row & 7)))*8];
      }
  }
  #pragma unroll
  for (int kh = 0; kh < 2; kh++)
    #pragma unroll
    for (int jj = 0; jj < 2; jj++) {
      int row = QN*128 + wn*32 + jj*16 + rl;
      bfr[kh][jj] = *(const bf16x8*)&bB[(size_t)(row*8 + ((kh*4 + q) ^ (row & 7)))*8];
    }
}

template<int QM, int QN>
__device__ __forceinline__ void qmma(bf16x8 (&af)[2][4], bf16x8 (&bfr)[2][2],
    f32x4 (&acc)[2][2][4][2])
{
  __builtin_amdgcn_sched_barrier(0);     // pin reads+stage before the barrier
  __builtin_amdgcn_s_barrier();
  asm volatile("s_waitcnt lgkmcnt(0)" ::: "memory");
  __builtin_amdgcn_sched_barrier(0);     // rule #18: MFMA must not hoist past lgkm
  __builtin_amdgcn_s_setprio(1);
  #pragma unroll
  for (int kh = 0; kh < 2; kh++)
    #pragma unroll
    for (int ii = 0; ii < 4; ii++)
      #pragma unroll
      for (int jj = 0; jj < 2; jj++)
        acc[QM][QN][ii][jj] = __builtin_amdgcn_mfma_f32_16x16x32_bf16(
            af[kh][ii], bfr[kh][jj], acc[QM][QN][ii][jj], 0, 0, 0);
  __builtin_amdgcn_s_setprio(0);
  __builtin_amdgcn_sched_barrier(0);
  __builtin_amdgcn_s_barrier();
}

// ---------------- 256x128 outproj helpers (round-2, unchanged) ----------------
template<int K>
__device__ __forceinline__ void stage_tile(const ushort* __restrict__ A,
    const ushort* __restrict__ W, int m0, int n0, int tid, int t,
    ushort* lA, ushort* lB)
{
  const int k0 = t * 64;
  #pragma unroll
  for (int it = 0; it < 4; it++) {          // A: 256 rows x 8 granules
    int s = it*512 + tid;
    int row = s >> 3;
    int g = (s & 7) ^ (row & 7);
    async_ld16(A + (size_t)(m0 + row)*K + k0 + g*8, lA + (size_t)s*8);
  }
  #pragma unroll
  for (int it = 0; it < 2; it++) {          // B: 128 rows x 8 granules
    int s = it*512 + tid;
    int row = s >> 3;
    int g = (s & 7) ^ (row & 7);
    async_ld16(W + (size_t)(n0 + row)*K + k0 + g*8, lB + (size_t)s*8);
  }
}

__device__ __forceinline__ void compute_tile(const ushort* lA, const ushort* lB,
    int wr, int wc, int rl, int q, f32x4 acc[4][4])
{
  #pragma unroll
  for (int kh = 0; kh < 2; kh++) {
    bf16x8 af[4], bfr[4];
    #pragma unroll
    for (int i = 0; i < 4; i++) {
      int row = wr*64 + i*16 + rl;
      af[i] = *(const bf16x8*)&lA[(size_t)(row*8 + ((kh*4 + q) ^ (row & 7)))*8];
    }
    #pragma unroll
    for (int j = 0; j < 4; j++) {
      int row = wc*64 + j*16 + rl;
      bfr[j] = *(const bf16x8*)&lB[(size_t)(row*8 + ((kh*4 + q) ^ (row & 7)))*8];
    }
    #pragma unroll
    for (int i = 0; i < 4; i++)
      #pragma unroll
      for (int j = 0; j < 4; j++)
        acc[i][j] = __builtin_amdgcn_mfma_f32_16x16x32_bf16(af[i], bfr[j], acc[i][j], 0, 0, 0);
  }
}

// ---------------- weight fp32 -> bf16 converters ----------------
__global__ __launch_bounds__(256) void convert_win_kernel(const float* __restrict__ W,
                                                          ushort* __restrict__ Wb)
{
  size_t i = (size_t)blockIdx.x*256 + threadIdx.x;
  Wb[i] = (i < (size_t)DINPROJ*DMODEL) ? f2b(W[i]) : (ushort)0;
}

__global__ __launch_bounds__(256) void convert_wout_kernel(const float* __restrict__ W,
                                                           ushort* __restrict__ Wb)
{
  size_t i = (size_t)blockIdx.x*256 + threadIdx.x;
  Wb[i] = f2b(W[i]);
}

// ---------------- LayerNorm -> h (bf16) ----------------
__global__ __launch_bounds__(256) void ln_kernel(const float* __restrict__ x,
    const float* __restrict__ w, const float* __restrict__ bias, ushort* __restrict__ h)
{
  const int row = blockIdx.x;
  const int t = threadIdx.x;
  const float* xr = x + (size_t)row * DMODEL;
  float v[4];
  float s = 0.f;
  #pragma unroll
  for (int i = 0; i < 4; i++) { v[i] = xr[t + i*256]; s += v[i]; }
  __shared__ float red[4];
  #pragma unroll
  for (int o = 32; o > 0; o >>= 1) s += __shfl_down(s, o, 64);
  if ((t & 63) == 0) red[t >> 6] = s;
  __syncthreads();
  float mean = (red[0]+red[1]+red[2]+red[3]) * (1.f/DMODEL);
  float vs = 0.f;
  #pragma unroll
  for (int i = 0; i < 4; i++) { float d = v[i]-mean; vs += d*d; }
  #pragma unroll
  for (int o = 32; o > 0; o >>= 1) vs += __shfl_down(vs, o, 64);
  __syncthreads();
  if ((t & 63) == 0) red[t >> 6] = vs;
  __syncthreads();
  float rstd = rsqrtf((red[0]+red[1]+red[2]+red[3]) * (1.f/DMODEL) + 1e-5f);
  ushort* hr = h + (size_t)row * DMODEL;
  #pragma unroll
  for (int i = 0; i < 4; i++) {
    int c = t + i*256;
    hr[c] = f2b((v[i]-mean)*rstd*w[c] + bias[c]);
  }
}

// ---------------- in_proj GEMM: 256x256, m201-style quadrant phases ----------------
// grid 576 (1-D): xcd = bid&7 owns m-blocks [4*xcd, 4*xcd+4), n-fastest within.
__global__ __launch_bounds__(512, 1) void gemm_inproj_8ph(const ushort* __restrict__ A,
    const ushort* __restrict__ W, ushort* __restrict__ z, ushort* __restrict__ xbc,
    float* __restrict__ dtr, const float* __restrict__ dtb)
{
  __shared__ ushort smem[65536];            // 128KB: buf d at d*32768 (A 16384, B 16384)
  const int tid = threadIdx.x;
  const int lane = tid & 63;
  const int w = tid >> 6;
  const int wq = w >> 2;                    // 0..1 (M within quadrant)
  const int wn = w & 3;                     // 0..3 (N within quadrant)
  const int rl = lane & 15;
  const int q  = lane >> 4;

  const int orig = blockIdx.x;              // [0,576)
  const int xcd  = orig & 7;
  const int jj_  = orig >> 3;               // [0,72)
  const int m0 = (xcd*4 + jj_/18) * 256;    // A panel pinned per XCD
  const int n0 = (jj_ % 18) * 256;          // n-fastest

  f32x4 acc[2][2][4][2];
  #pragma unroll
  for (int a = 0; a < 2; a++)
    #pragma unroll
    for (int b = 0; b < 2; b++)
      #pragma unroll
      for (int c = 0; c < 4; c++)
        #pragma unroll
        for (int d = 0; d < 2; d++) acc[a][b][c][d] = (f32x4)(0.f);

  bf16x8 af[2][4], bfr[2][2];
  constexpr int NT = DMODEL / 64;           // 16 K-tiles

  // prologue: t0 all 4 halves + t1 {A-lo,B-lo}  [12 insts]; gate t0, keep t1 flying
  {
    ushort* A0 = smem;            ushort* B0 = smem + 16384;
    ushort* A1 = smem + 32768;    ushort* B1 = A1 + 16384;
    stage_half<DMODEL>(A, m0+0,   0,  tid, A0);
    stage_half<DMODEL>(W, n0+0,   0,  tid, B0);
    stage_half<DMODEL>(A, m0+128, 0,  tid, A0 + 8192);
    stage_half<DMODEL>(W, n0+128, 0,  tid, B0 + 8192);
    stage_half<DMODEL>(A, m0+0,   64, tid, A1);
    stage_half<DMODEL>(W, n0+0,   64, tid, B1);
    VMG(4);                                 // t0's 8 insts done; t1's 4 in flight
    __builtin_amdgcn_s_barrier();           // t0 visible block-wide
    __builtin_amdgcn_sched_barrier(0);
  }

  // main loop: t = 0..NT-3; one VMG(4) per K-tile (at p4, before its barriers)
  for (int t = 0; t < NT-2; t++) {
    const int d = t & 1;
    const ushort* bA = smem + d*32768;
    const ushort* bB = bA + 16384;
    ushort* nA = smem + (d^1)*32768;        // buf for tile t+1
    ushort* nB = nA + 16384;
    ushort* sA = smem + d*32768;            // buf for tile t+2 (same as t)
    ushort* sB = sA + 16384;
    // p1: Q(0,0) [A-lo, B-lo]; stage t+1 A-hi
    qreads<0,0,true >(bA, bB, wq, wn, rl, q, af, bfr);
    stage_half<DMODEL>(A, m0+128, (t+1)*64, tid, nA + 8192);
    qmma<0,0>(af, bfr, acc);
    // p2: Q(0,1) [B-hi]; stage t+1 B-hi
    qreads<0,1,false>(bA, bB, wq, wn, rl, q, af, bfr);
    stage_half<DMODEL>(W, n0+128, (t+1)*64, tid, nB + 8192);
    qmma<0,1>(af, bfr, acc);
    // p3: Q(1,0) [A-hi, B-lo]; stage t+2 A-lo (A-lo reads done at p1 lgkm)
    qreads<1,0,true >(bA, bB, wq, wn, rl, q, af, bfr);
    stage_half<DMODEL>(A, m0+0, (t+2)*64, tid, sA);
    qmma<1,0>(af, bfr, acc);
    // p4: Q(1,1) [B-hi]; stage t+2 B-lo (B-lo reads done at p3 lgkm); gate t+1
    qreads<1,1,false>(bA, bB, wq, wn, rl, q, af, bfr);
    stage_half<DMODEL>(W, n0+0, (t+2)*64, tid, sB);
    VMG(4);                                 // t+1's 8 insts done; t+2's 4 flying
    qmma<1,1>(af, bfr, acc);
  }
  // peeled t = NT-2: stage only t+1's {A-hi,B-hi}; drain gate VMG(0) at p4
  {
    const int t = NT-2;
    const int d = t & 1;
    const ushort* bA = smem + d*32768;
    const ushort* bB = bA + 16384;
    ushort* nA = smem + (d^1)*32768;
    ushort* nB = nA + 16384;
    qreads<0,0,true >(bA, bB, wq, wn, rl, q, af, bfr);
    stage_half<DMODEL>(A, m0+128, (t+1)*64, tid, nA + 8192);
    qmma<0,0>(af, bfr, acc);
    qreads<0,1,false>(bA, bB, wq, wn, rl, q, af, bfr);
    stage_half<DMODEL>(W, n0+128, (t+1)*64, tid, nB + 8192);
    qmma<0,1>(af, bfr, acc);
    qreads<1,0,true >(bA, bB, wq, wn, rl, q, af, bfr);
    qmma<1,0>(af, bfr, acc);
    qreads<1,1,false>(bA, bB, wq, wn, rl, q, af, bfr);
    VMG(0);                                 // all of tile NT-1 landed
    qmma<1,1>(af, bfr, acc);
  }
  // peeled t = NT-1: no stages, no gates (covered by NT-2 p4's VMG(0)+barrier)
  {
    const int d = (NT-1) & 1;
    const ushort* bA = smem + d*32768;
    const ushort* bB = bA + 16384;
    qreads<0,0,true >(bA, bB, wq, wn, rl, q, af, bfr);
    qmma<0,0>(af, bfr, acc);
    qreads<0,1,false>(bA, bB, wq, wn, rl, q, af, bfr);
    qmma<0,1>(af, bfr, acc);
    qreads<1,0,true >(bA, bB, wq, wn, rl, q, af, bfr);
    qmma<1,0>(af, bfr, acc);
    qreads<1,1,false>(bA, bB, wq, wn, rl, q, af, bfr);
    qmma<1,1>(af, bfr, acc);
  }

  const int colL = lane & 15;
  const int rowQ = (lane >> 4) * 4;
  if (n0 < DINNER + CONVCH) {
    // swizzled bf16 restage of the 256x256 tile (128KB), then coalesced 16B stores
    #pragma unroll
    for (int qm = 0; qm < 2; qm++)
      #pragma unroll
      for (int qn = 0; qn < 2; qn++)
        #pragma unroll
        for (int ii = 0; ii < 4; ii++)
          #pragma unroll
          for (int jj = 0; jj < 2; jj++) {
            int col = qn*128 + wn*32 + jj*16 + colL;
            int g = col >> 3;
            #pragma unroll
            for (int r = 0; r < 4; r++) {
              int row = qm*128 + wq*64 + ii*16 + rowQ + r;
              int p = (g & 24) | ((g ^ row) & 7);
              smem[row*256 + p*8 + (col & 7)] = f2b(acc[qm][qn][ii][jj][r]);
            }
          }
    __syncthreads();
    ushort* outp; int coff, ncols;
    if (n0 < DINNER) { outp = z;   coff = n0;          ncols = DINNER; }
    else             { outp = xbc; coff = n0 - DINNER; ncols = CONVCH; }
    #pragma unroll
    for (int it = 0; it < 16; it++) {
      int idx = tid + it*512;               // 256 rows x 32 granules = 8192
      int row = idx >> 5, g = idx & 31;
      int p = (g & 24) | ((g ^ row) & 7);
      *(uint4*)(outp + (size_t)(m0 + row)*ncols + coff + g*8) =
          *(const uint4*)&smem[row*256 + p*8];
    }
  } else {
    // dt tile (n0 == 4352): only local cols [0,32) real (qn=0, wn=0)
    if (wn == 0) {
      #pragma unroll
      for (int qm = 0; qm < 2; qm++)
        #pragma unroll
        for (int ii = 0; ii < 4; ii++)
          #pragma unroll
          for (int jj = 0; jj < 2; jj++) {
            int lc = jj*16 + colL;          // < 32
            float bb = dtb[lc];
            #pragma unroll
            for (int r = 0; r < 4; r++) {
              float v = acc[qm][0][ii][jj][r] + bb;
              v = (v > 20.f) ? v : log1pf(expf(v));
              dtr[(size_t)(m0 + qm*128 + wq*64 + ii*16 + rowQ + r)*NHEADS + lc] = v;
            }
          }
    }
  }
}

// ---------------- out_proj GEMM: 256x128, counted vmcnt, XCD m-partition ----------------
__global__ __launch_bounds__(512, 1) void gemm_outproj_big(const ushort* __restrict__ A,
    const ushort* __restrict__ W, const float* __restrict__ x, float* __restrict__ out)
{
  __shared__ ushort smem[49152];            // 96KB
  ushort* lA0 = smem;                       // 2 x 16384
  ushort* lB0 = smem + 32768;               // 2 x 8192
  float* fbuf = (float*)smem;               // epilogue: 128x128 f32 = 64KB
  const int tid = threadIdx.x;
  const int lane = tid & 63;
  const int w = tid >> 6;
  const int wr = w >> 1;                    // 0..3 (M)
  const int wc = w & 1;                     // 0..1 (N)
  const int rl = lane & 15;
  const int q  = lane >> 4;

  const int orig = blockIdx.x;              // [0,256)
  const int xcd  = orig & 7;
  const int jj   = orig >> 3;               // [0,32)
  const int m0 = (xcd*4 + (jj >> 3)) * 256;
  const int n0 = (jj & 7) * 128;

  f32x4 acc[4][4];
  #pragma unroll
  for (int i = 0; i < 4; i++)
    #pragma unroll
    for (int j = 0; j < 4; j++) acc[i][j] = (f32x4)(0.f);

  constexpr int NT = DINNER / 64;           // 32 K-tiles
  stage_tile<DINNER>(A, W, m0, n0, tid, 0, lA0, lB0);
  for (int t = 0; t < NT; t++) {
    const ushort* cA = lA0 + (size_t)(t & 1) * 16384;
    const ushort* cB = lB0 + (size_t)(t & 1) * 8192;
    if (t + 1 < NT) {
      stage_tile<DINNER>(A, W, m0, n0, tid, t + 1,
                         lA0 + (size_t)((t+1) & 1) * 16384,
                         lB0 + (size_t)((t+1) & 1) * 8192);
      asm volatile("s_waitcnt vmcnt(6)" ::: "memory");   // t's 6 loads done; t+1's fly
    } else {
      asm volatile("s_waitcnt vmcnt(0)" ::: "memory");
    }
    __builtin_amdgcn_s_barrier();
    __builtin_amdgcn_sched_barrier(0);
    __builtin_amdgcn_s_setprio(1);
    compute_tile(cA, cB, wr, wc, rl, q, acc);
    __builtin_amdgcn_s_setprio(0);
    __builtin_amdgcn_sched_barrier(0);
    __builtin_amdgcn_s_barrier();
  }

  const int colL = lane & 15;
  const int rowQ = (lane >> 4) * 4;
  // fp32 restage in two 128-row halves (64KB each), fused residual add
  #pragma unroll
  for (int h = 0; h < 2; h++) {
    __syncthreads();
    if ((wr >> 1) == h) {                   // waves wr in {2h, 2h+1}
      #pragma unroll
      for (int i = 0; i < 4; i++)
        #pragma unroll
        for (int j = 0; j < 4; j++) {
          int col = wc*64 + j*16 + colL;
          int g = col >> 2;
          #pragma unroll
          for (int r = 0; r < 4; r++) {
            int row = (wr & 1)*64 + i*16 + rowQ + r;
            fbuf[row*128 + ((g ^ (row & 7)) << 2) + (col & 3)] = acc[i][j][r];
          }
        }
    }
    __syncthreads();
    #pragma unroll
    for (int it = 0; it < 8; it++) {
      int idx = tid + it*512;               // 128 rows x 32 float4 = 4096
      int row = idx >> 5, c4 = idx & 31;
      int gm = m0 + h*128 + row;
      float4 xv = *(const float4*)(x + (size_t)gm*DMODEL + n0 + c4*4);
      float4 vv = *(const float4*)&fbuf[row*128 + ((c4 ^ (row & 7)) << 2)];
      vv.x += xv.x; vv.y += xv.y; vv.z += xv.z; vv.w += xv.w;
      *(float4*)(out + (size_t)gm*DMODEL + n0 + c4*4) = vv;
    }
  }
}

// ---------------- causal conv4 + SiLU, LDS row-tiled ----------------
__global__ __launch_bounds__(256) void conv_tiled(const ushort* __restrict__ xbc,
    const float* __restrict__ cw, const float* __restrict__ cb,
    ushort* __restrict__ xs, ushort* __restrict__ bcb)
{
  __shared__ ushort tile[35*256];
  const int tid = threadIdx.x;
  const int ch0 = blockIdx.x * 256;
  const int row0 = blockIdx.y * 32;
  const int l0 = row0 & (LSEQ-1);
  for (int idx = tid; idx < 35*32; idx += 256) {
    int r = idx >> 5, c16 = idx & 31;
    uint4 v = make_uint4(0,0,0,0);
    if (l0 + r - 3 >= 0)
      v = *(const uint4*)(xbc + (size_t)(row0 + r - 3)*CONVCH + ch0 + c16*8);
    *(uint4*)&tile[r*256 + c16*8] = v;
  }
  __syncthreads();
  const int ch = ch0 + tid;
  const float w0 = cw[ch*4+0], w1 = cw[ch*4+1], w2 = cw[ch*4+2], w3 = cw[ch*4+3];
  const float bias = cb[ch];
  const bool isX = (ch0 < DINNER);
  #pragma unroll 4
  for (int r = 0; r < 32; r++) {
    float acc = bias;
    acc = fmaf(b2f(tile[(r+0)*256 + tid]), w0, acc);
    acc = fmaf(b2f(tile[(r+1)*256 + tid]), w1, acc);
    acc = fmaf(b2f(tile[(r+2)*256 + tid]), w2, acc);
    acc = fmaf(b2f(tile[(r+3)*256 + tid]), w3, acc);
    float v = acc / (1.f + expf(-acc));
    if (isX) xs[(size_t)(row0 + r)*DINNER + ch] = f2b(v);
    else     bcb[(size_t)(row0 + r)*256 + (ch - DINNER)] = f2b(v);
  }
}

// ---------------- per-chunk states via MFMA: S[p][n] = sum_l Xw[l][p]*B[l][n] ----------------
__global__ __launch_bounds__(256) void states_mfma(
    const ushort* __restrict__ xs, const ushort* __restrict__ bcb, const float* __restrict__ dt,
    const float* __restrict__ A_log, ushort* __restrict__ S, float* __restrict__ asum)
{
  constexpr int LDP = 136;
  __shared__ ushort lBT[128*LDP];   // B^T[n][l]
  __shared__ ushort lXT[64*LDP];    // Xw^T[p][l]; reused for S restage
  __shared__ float dts[CHUNKL], acs[CHUNKL];
  __shared__ float wtot;
  const int hh = blockIdx.x, c = blockIdx.y, b = blockIdx.z;
  const int tid = threadIdx.x;
  const int lane = tid & 63;
  const int w = tid >> 6;
  const int rbase = b*LSEQ + c*CHUNKL;
  const size_t sbase = (size_t)((b*NCHUNK + c)*NHEADS + hh) * 8192;

  float pre = 0.f;
  if (tid < 128) {
    float myv = dt[(size_t)(rbase + tid)*NHEADS + hh];
    dts[tid] = myv;
    pre = myv;
    #pragma unroll
    for (int o = 1; o < 64; o <<= 1) {
      float u = __shfl_up(pre, o, 64);
      if ((tid & 63) >= o) pre += u;
    }
    if (tid == 63) wtot = pre;
  }
  #pragma unroll
  for (int it = 0; it < 8; it++) {
    int chunk = tid + it*256;
    int l = chunk >> 4, n8 = chunk & 15;
    ushort tmp[8];
    *(uint4*)tmp = *(const uint4*)(bcb + (size_t)(rbase + l)*256 + n8*8);
    #pragma unroll
    for (int u = 0; u < 8; u++) lBT[(n8*8+u)*LDP + l] = tmp[u];
  }
  __syncthreads();
  float alast_loc = 0.f;
  if (tid < 128) {
    float Aval = -expf(A_log[hh]);
    float a = (pre + ((tid >= 64) ? wtot : 0.f)) * Aval;
    acs[tid] = a;
    if (tid == 127) { asum[(b*NCHUNK + c)*NHEADS + hh] = a; }
  }
  __syncthreads();
  alast_loc = acs[CHUNKL-1];
  #pragma unroll
  for (int it = 0; it < 4; it++) {
    int chunk = tid + it*256;
    int l = chunk >> 3, p8 = (chunk & 7)*8;
    ushort tmp[8];
    *(uint4*)tmp = *(const uint4*)(xs + (size_t)(rbase + l)*DINNER + hh*HEADDIM + p8);
    float wl = dts[l] * expf(alast_loc - acs[l]);
    #pragma unroll
    for (int u = 0; u < 8; u++) lXT[(p8+u)*LDP + l] = f2b(b2f(tmp[u]) * wl);
  }
  __syncthreads();

  const int rl = lane & 15;
  const int kq = (lane >> 4) * 8;
  const int nb = w * 32;
  f32x4 acc[4][2];
  #pragma unroll
  for (int i = 0; i < 4; i++) { acc[i][0] = (f32x4)(0.f); acc[i][1] = (f32x4)(0.f); }
  #pragma unroll
  for (int k0 = 0; k0 < 128; k0 += 32) {
    bf16x8 af[4], bfr[2];
    #pragma unroll
    for (int i = 0; i < 4; i++) af[i]  = *(const bf16x8*)&lXT[(i*16 + rl)*LDP + k0 + kq];
    #pragma unroll
    for (int j = 0; j < 2; j++) bfr[j] = *(const bf16x8*)&lBT[(nb + j*16 + rl)*LDP + k0 + kq];
    #pragma unroll
    for (int i = 0; i < 4; i++)
      #pragma unroll
      for (int j = 0; j < 2; j++)
        acc[i][j] = __builtin_amdgcn_mfma_f32_16x16x32_bf16(af[i], bfr[j], acc[i][j], 0, 0, 0);
  }
  __syncthreads();
  const int colL = lane & 15;
  const int rowQ = (lane >> 4) * 4;
  #pragma unroll
  for (int i = 0; i < 4; i++)
    #pragma unroll
    for (int j = 0; j < 2; j++)
      #pragma unroll
      for (int r = 0; r < 4; r++)
        lXT[(i*16 + rowQ + r)*LDP + nb + j*16 + colL] = f2b(acc[i][j][r]);
  __syncthreads();
  #pragma unroll
  for (int it = 0; it < 4; it++) {
    int idx = tid + it*256;
    int row = idx >> 4, c8 = idx & 15;
    *(uint4*)(S + sbase + row*128 + c8*8) = *(const uint4*)&lXT[row*LDP + c8*8];
  }
}

// ---------------- inter-chunk scan, split 4x over state slices ----------------
__global__ __launch_bounds__(256) void scan_kernel(ushort* __restrict__ S, const float* __restrict__ asum)
{
  const int hh = blockIdx.x, sl = blockIdx.y, b = blockIdx.z;
  const int base0 = sl*2048 + threadIdx.x;
  float carry[8];
  #pragma unroll
  for (int i = 0; i < 8; i++) carry[i] = 0.f;
  for (int c = 0; c < NCHUNK; c++) {
    ushort* Sp = S + (size_t)((b*NCHUNK + c)*NHEADS + hh) * 8192;
    float dec = expf(asum[(b*NCHUNK + c)*NHEADS + hh]);
    #pragma unroll
    for (int i = 0; i < 8; i++) {
      int idx = base0 + i*256;
      float sv = b2f(Sp[idx]);
      Sp[idx] = f2b(carry[i]);
      carry[i] = fmaf(dec, carry[i], sv);
    }
  }
}

// ---------------- yssd MFMA v2: direct-global fragments for C/B/P; LDS only M + X^T ----------------
__global__ __launch_bounds__(256) void yssd_mfma(
    const ushort* __restrict__ xs, const ushort* __restrict__ bcb, const float* __restrict__ dt,
    const float* __restrict__ A_log, const float* __restrict__ Dvec,
    const ushort* __restrict__ S, ushort* __restrict__ y)
{
  constexpr int LDP = 136;
  __shared__ ushort lM [128*LDP];   // M[l][s]
  __shared__ ushort lXT[64*LDP];    // X^T[p][s]
  __shared__ float dts[CHUNKL], acs[CHUNKL];
  __shared__ float wtot;
  const int hh = blockIdx.x, c = blockIdx.y, b = blockIdx.z;
  const int tid = threadIdx.x;
  const int lane = tid & 63;
  const int w = tid >> 6;
  const int rbase = b*LSEQ + c*CHUNKL;
  const size_t sbase = (size_t)((b*NCHUNK + c)*NHEADS + hh) * 8192;
  const ushort* Bg = bcb + (size_t)rbase*256;        // B row s at Bg + s*256
  const ushort* Cg = Bg + 128;                       // C row l at Cg + l*256

  // stage X^T (transposing scatter) — the only global->LDS staging
  #pragma unroll
  for (int it = 0; it < 4; it++) {
    int chunk = tid + it*256;
    int s = chunk >> 3, p0 = (chunk & 7)*8;
    ushort tmp[8];
    *(uint4*)tmp = *(const uint4*)(xs + (size_t)(rbase + s)*DINNER + hh*HEADDIM + p0);
    #pragma unroll
    for (int u = 0; u < 8; u++) lXT[(p0+u)*LDP + s] = tmp[u];
  }
  // dt load + wave-parallel inclusive scan
  float pre = 0.f;
  if (tid < 128) {
    float myv = dt[(size_t)(rbase + tid)*NHEADS + hh];
    dts[tid] = myv;
    pre = myv;
    #pragma unroll
    for (int o = 1; o < 64; o <<= 1) {
      float u = __shfl_up(pre, o, 64);
      if ((tid & 63) >= o) pre += u;
    }
    if (tid == 63) wtot = pre;
  }
  __syncthreads();
  if (tid < 128) {
    float Aval = -expf(A_log[hh]);
    acs[tid] = (pre + ((tid >= 64) ? wtot : 0.f)) * Aval;
  }

  const int rl = lane & 15;
  const int kq = (lane >> 4) * 8;
  const int colL = lane & 15;
  const int rowQ = (lane >> 4) * 4;

  // ---- GEMM1: G[l][s] = sum_n C[l][n]*B[s][n], fragments direct from global
  const int wm = (w & 1) * 64;
  const int wn = (w >> 1) * 64;
  f32x4 G[4][4];
  #pragma unroll
  for (int i = 0; i < 4; i++)
    #pragma unroll
    for (int j = 0; j < 4; j++) G[i][j] = (f32x4)(0.f);
  #pragma unroll
  for (int k0 = 0; k0 < 128; k0 += 32) {
    bf16x8 af[4], bfr[4];
    #pragma unroll
    for (int i = 0; i < 4; i++) af[i]  = *(const bf16x8*)(Cg + (size_t)(wm + i*16 + rl)*256 + k0 + kq);
    #pragma unroll
    for (int j = 0; j < 4; j++) bfr[j] = *(const bf16x8*)(Bg + (size_t)(wn + j*16 + rl)*256 + k0 + kq);
    #pragma unroll
    for (int i = 0; i < 4; i++)
      #pragma unroll
      for (int j = 0; j < 4; j++)
        G[i][j] = __builtin_amdgcn_mfma_f32_16x16x32_bf16(af[i], bfr[j], G[i][j], 0, 0, 0);
  }
  __syncthreads();   // acs (written pre-GEMM1 by tid<128) visible to all; XT staged

  // ---- M[l][s] = (l>=s) ? G*exp(acs[l]-acs[s])*dt[s] : 0  -> lM
  #pragma unroll
  for (int j = 0; j < 4; j++) {
    int sIdx = wn + j*16 + colL;
    float as = acs[sIdx];
    float ds = dts[sIdx];
    #pragma unroll
    for (int i = 0; i < 4; i++) {
      #pragma unroll
      for (int r = 0; r < 4; r++) {
        int lIdx = wm + i*16 + rowQ + r;
        float m = (lIdx >= sIdx) ? G[i][j][r] * expf(acs[lIdx] - as) * ds : 0.f;
        lM[lIdx*LDP + sIdx] = f2b(m);
      }
    }
  }

  // ---- GEMM-off: Y[l][p] = sum_n C[l][n]*P[p][n], C and P direct from global
  const int om = w * 32;
  f32x4 Y[2][4];
  #pragma unroll
  for (int i = 0; i < 2; i++)
    #pragma unroll
    for (int j = 0; j < 4; j++) Y[i][j] = (f32x4)(0.f);
  #pragma unroll
  for (int k0 = 0; k0 < 128; k0 += 32) {
    bf16x8 a2[2], b2[4];
    #pragma unroll
    for (int i = 0; i < 2; i++) a2[i] = *(const bf16x8*)(Cg + (size_t)(om + i*16 + rl)*256 + k0 + kq);
    #pragma unroll
    for (int j = 0; j < 4; j++) b2[j] = *(const bf16x8*)(S + sbase + (size_t)(j*16 + rl)*128 + k0 + kq);
    #pragma unroll
    for (int i = 0; i < 2; i++)
      #pragma unroll
      for (int j = 0; j < 4; j++)
        Y[i][j] = __builtin_amdgcn_mfma_f32_16x16x32_bf16(a2[i], b2[j], Y[i][j], 0, 0, 0);
  }
  #pragma unroll
  for (int i = 0; i < 2; i++)
    #pragma unroll
    for (int r = 0; r < 4; r++) {
      float e = expf(acs[om + i*16 + rowQ + r]);
      #pragma unroll
      for (int j = 0; j < 4; j++) Y[i][j][r] *= e;
    }
  __syncthreads();   // lM writes visible

  // ---- GEMM-diag: Y[l][p] += sum_s M[l][s]*XT[p][s]
  #pragma unroll
  for (int k0 = 0; k0 < 128; k0 += 32) {
    bf16x8 a3[2], b3[4];
    #pragma unroll
    for (int i = 0; i < 2; i++) a3[i] = *(const bf16x8*)&lM[(om + i*16 + rl)*LDP + k0 + kq];
    #pragma unroll
    for (int j = 0; j < 4; j++) b3[j] = *(const bf16x8*)&lXT[(j*16 + rl)*LDP + k0 + kq];
    #pragma unroll
    for (int i = 0; i < 2; i++)
      #pragma unroll
      for (int j = 0; j < 4; j++)
        Y[i][j] = __builtin_amdgcn_mfma_f32_16x16x32_bf16(a3[i], b3[j], Y[i][j], 0, 0, 0);
  }

  // ---- epilogue: += D*xs, write bf16
  const float Dh = Dvec[hh];
  #pragma unroll
  for (int i = 0; i < 2; i++) {
    #pragma unroll
    for (int r = 0; r < 4; r++) {
      int lIdx = om + i*16 + rowQ + r;
      ushort* yrow = y + (size_t)(rbase + lIdx)*DINNER + hh*HEADDIM;
      #pragma unroll
      for (int j = 0; j < 4; j++) {
        int p = j*16 + colL;
        float val = Y[i][j][r] + Dh * b2f(lXT[p*LDP + lIdx]);
        yrow[p] = f2b(val);
      }
    }
  }
}

// ---------------- gated RMSNorm (in place on y, bf16) ----------------
__global__ __launch_bounds__(256) void rmsnorm_kernel(ushort* __restrict__ y,
    const ushort* __restrict__ z, const float* __restrict__ nw)
{
  const int row = blockIdx.x;
  const int t = threadIdx.x;
  ushort* yr = y + (size_t)row*DINNER;
  const ushort* zr = z + (size_t)row*DINNER;
  float v[8];
  float ss = 0.f;
  #pragma unroll
  for (int i = 0; i < 8; i++) {
    int c = t + i*256;
    float zz = b2f(zr[c]);
    float g = b2f(yr[c]) * (zz / (1.f + expf(-zz)));
    v[i] = g;
    ss += g*g;
  }
  #pragma unroll
  for (int o = 32; o > 0; o >>= 1) ss += __shfl_down(ss, o, 64);
  __shared__ float red[4];
  if ((t & 63) == 0) red[t >> 6] = ss;
  __syncthreads();
  float scale = rsqrtf((red[0]+red[1]+red[2]+red[3]) * (1.f/DINNER) + 1e-5f);
  #pragma unroll
  for (int i = 0; i < 8; i++) {
    int c = t + i*256;
    yr[c] = f2b(v[i]*scale*nw[c]);
  }
}

extern "C" void kernel_launch(void* const* d_in, const int* in_sizes, int n_in,
                              void* d_out, int out_size, void* d_ws, size_t ws_size,
                              hipStream_t stream)
{
  const float* x    = (const float*)d_in[0];
  const float* lnw  = (const float*)d_in[1];
  const float* lnb  = (const float*)d_in[2];
  const float* win  = (const float*)d_in[3];
  const float* cw   = (const float*)d_in[4];
  const float* cb   = (const float*)d_in[5];
  const float* dtb  = (const float*)d_in[6];
  const float* alog = (const float*)d_in[7];
  const float* dvec = (const float*)d_in[8];
  const float* nw   = (const float*)d_in[9];
  const float* wout = (const float*)d_in[10];
  float* out = (float*)d_out;
  char* ws = (char*)d_ws;
  (void)in_sizes; (void)n_in; (void)out_size;

  if (ws_size < B_END) return;  // workspace too small: fail cleanly, don't fault

  ushort* zb   = (ushort*)(ws + B_Z);
  ushort* xbcb = (ushort*)(ws + B_XBC);
  float*  dtr  = (float*) (ws + B_DT);
  ushort* xsb  = (ushort*)(ws + B_XS);
  ushort* bcb  = (ushort*)(ws + B_BC);
  ushort* yb   = (ushort*)(ws + B_Y);
  float*  asum = (float*) (ws + B_ASUM);
  ushort* Sb   = xbcb;                                        // aliases xbc (dead after conv)
  ushort* hb   = yb;                                          // aliases y[0 : 16.8MB]
  ushort* winB = (ushort*)(ws + B_Y + (size_t)ROWS*DMODEL*2); // aliases y[16.8MB : 26.2MB) (4608x1024 bf16 = 9.44MB)
  ushort* woutB= (ushort*)(ws + B_XBC + (size_t)BATCH*NCHUNK*NHEADS*HEADDIM*DSTATE*2); // XBC tail (4.19MB)

  hipLaunchKernelGGL(convert_win_kernel, dim3((NPAD*DMODEL)/256), dim3(256), 0, stream, win, winB);
  hipLaunchKernelGGL(ln_kernel, dim3(ROWS), dim3(256), 0, stream, x, lnw, lnb, hb);
  hipLaunchKernelGGL(gemm_inproj_8ph, dim3(576), dim3(512), 0, stream, hb, winB, zb, xbcb, dtr, dtb);
  hipLaunchKernelGGL(conv_tiled, dim3(9, ROWS/32), dim3(256), 0, stream, xbcb, cw, cb, xsb, bcb);
  hipLaunchKernelGGL(convert_wout_kernel, dim3((DMODEL*DINNER)/256), dim3(256), 0, stream, wout, woutB);
  hipLaunchKernelGGL(states_mfma, dim3(NHEADS, NCHUNK, BATCH), dim3(256), 0, stream,
                     xsb, bcb, dtr, alog, Sb, asum);
  hipLaunchKernelGGL(scan_kernel, dim3(NHEADS, 4, BATCH), dim3(256), 0, stream, Sb, asum);
  hipLaunchKernelGGL(yssd_mfma, dim3(NHEADS, NCHUNK, BATCH), dim3(256), 0, stream,
                     xsb, bcb, dtr, alog, dvec, Sb, yb);
  hipLaunchKernelGGL(rmsnorm_kernel, dim3(ROWS), dim3(256), 0, stream, yb, zb, nw);
  hipLaunchKernelGGL(gemm_outproj_big, dim3(256), dim3(512), 0, stream, yb, woutB, x, out);
}

// Round 6
// 461.416 us; speedup vs baseline: 1.0320x; 1.0157x over previous
//
#include <hip/hip_runtime.h>
#include <math.h>

#define BATCH   4
#define LSEQ    2048
#define DMODEL  1024
#define DSTATE  128
#define HEADDIM 64
#define DINNER  2048
#define NHEADS  32
#define CONVCH  2304
#define DINPROJ 4384
#define NPAD    4608
#define CHUNKL  128
#define NCHUNK  16
#define ROWS    (BATCH*LSEQ)

// ---------------- workspace layout (BYTE offsets) ----------------
#define B_Z     ((size_t)0)                              // ROWS*DINNER bf16
#define B_XBC   (B_Z   + (size_t)ROWS*DINNER*2)          // ROWS*CONVCH bf16; S aliases first 33.55MB; Wout bf16 aliases tail 4.19MB
#define B_DT    (B_XBC + (size_t)ROWS*CONVCH*2)          // ROWS*NHEADS fp32
#define B_XS    (B_DT  + (size_t)ROWS*NHEADS*4)          // ROWS*DINNER bf16
#define B_BC    (B_XS  + (size_t)ROWS*DINNER*2)          // ROWS*256 bf16
#define B_Y     (B_BC  + (size_t)ROWS*256*2)             // ROWS*DINNER bf16; h bf16 aliases [0,16.8MB); Win bf16 aliases [16.8MB,26.2MB)
#define B_ASUM  (B_Y   + (size_t)ROWS*DINNER*2)          // BATCH*NCHUNK*NHEADS fp32
#define B_END   (B_ASUM + (size_t)BATCH*NCHUNK*NHEADS*4) // ~137 MB total

typedef __attribute__((ext_vector_type(8))) short bf16x8;
typedef __attribute__((ext_vector_type(4))) float f32x4;

__device__ __forceinline__ float b2f(ushort u) {
  union { uint32_t i; float f; } v; v.i = ((uint32_t)u) << 16; return v.f;
}
__device__ __forceinline__ ushort f2b(float f) {
  union { float f; uint32_t i; } v; v.f = f;
  uint32_t r = (v.i + 0x7FFFu + ((v.i >> 16) & 1u)) >> 16;
  return (ushort)r;
}

__device__ __forceinline__ void async_ld16(const void* g, void* l) {
  __builtin_amdgcn_global_load_lds(
      (const __attribute__((address_space(1))) unsigned int*)g,
      (__attribute__((address_space(3))) unsigned int*)l, 16, 0, 0);
}

// ================= 256x128 inproj helpers (round-1 measured-best) =================
// 512 thr = 8 waves as 4M x 2N; per-wave output 64x64 (acc[4][4]).
// LDS: lA 2 x 256x64 bf16 (2x32KB), lB 2 x 128x64 bf16 (2x16KB) = 96KB.
// XOR-swizzle: 16B granule g of tile row r lives at slot r*8 + (g ^ (r&7)).
// Schedule: stage(t+1) -> setprio MFMA(t) -> __syncthreads() (drain lands
// after a full compute phase; one barrier per K-tile).
template<int K>
__device__ __forceinline__ void stage_tile(const ushort* __restrict__ A,
    const ushort* __restrict__ W, int m0, int n0, int tid, int t,
    ushort* lA, ushort* lB)
{
  const int k0 = t * 64;
  #pragma unroll
  for (int it = 0; it < 4; it++) {          // A: 256 rows x 8 granules = 2048 slots
    int s = it*512 + tid;
    int row = s >> 3;
    int g = (s & 7) ^ (row & 7);
    async_ld16(A + (size_t)(m0 + row)*K + k0 + g*8, lA + (size_t)s*8);
  }
  #pragma unroll
  for (int it = 0; it < 2; it++) {          // B: 128 rows x 8 granules = 1024 slots
    int s = it*512 + tid;
    int row = s >> 3;
    int g = (s & 7) ^ (row & 7);
    async_ld16(W + (size_t)(n0 + row)*K + k0 + g*8, lB + (size_t)s*8);
  }
}

__device__ __forceinline__ void compute_tile(const ushort* lA, const ushort* lB,
    int wr, int wc, int rl, int q, f32x4 acc[4][4])
{
  #pragma unroll
  for (int kh = 0; kh < 2; kh++) {
    bf16x8 af[4], bfr[4];
    #pragma unroll
    for (int i = 0; i < 4; i++) {
      int row = wr*64 + i*16 + rl;
      af[i] = *(const bf16x8*)&lA[(size_t)(row*8 + ((kh*4 + q) ^ (row & 7)))*8];
    }
    #pragma unroll
    for (int j = 0; j < 4; j++) {
      int row = wc*64 + j*16 + rl;
      bfr[j] = *(const bf16x8*)&lB[(size_t)(row*8 + ((kh*4 + q) ^ (row & 7)))*8];
    }
    #pragma unroll
    for (int i = 0; i < 4; i++)
      #pragma unroll
      for (int j = 0; j < 4; j++)
        acc[i][j] = __builtin_amdgcn_mfma_f32_16x16x32_bf16(af[i], bfr[j], acc[i][j], 0, 0, 0);
  }
}

// ================= 128x128 shared core (round-0 measured-best, multi-block/CU) =================
// 256 thr = 4 waves as 2x2; single-buffered 32KB; stage->sync->compute per K-tile.
// Latency hidden by inter-block TLP (several blocks resident per CU).
template<int K>
__device__ __forceinline__ void gemm_core_swz(const ushort* __restrict__ A,
    const ushort* __restrict__ W, int m0, int n0, int tid,
    ushort* lA, ushort* lB, f32x4 acc[4][4])
{
  const int lane = tid & 63;
  const int w = tid >> 6;
  const int wm = (w & 1) * 64;
  const int wn = (w >> 1) * 64;
  const int rl = lane & 15;
  const int q  = lane >> 4;
  for (int k0 = 0; k0 < K; k0 += 64) {
    __syncthreads();
    #pragma unroll
    for (int is = 0; is < 4; is++) {
      int s = (w*4 + is)*64 + lane;
      int row = s >> 3;
      int g = (s & 7) ^ (row & 7);
      async_ld16(A + (size_t)(m0 + row)*K + k0 + g*8, lA + (size_t)s*8);
      async_ld16(W + (size_t)(n0 + row)*K + k0 + g*8, lB + (size_t)s*8);
    }
    __syncthreads();
    #pragma unroll
    for (int kh = 0; kh < 2; kh++) {
      bf16x8 af[4], bfr[4];
      #pragma unroll
      for (int i = 0; i < 4; i++) {
        int row = wm + i*16 + rl;
        af[i] = *(const bf16x8*)&lA[(size_t)(row*8 + ((kh*4 + q) ^ (row & 7)))*8];
      }
      #pragma unroll
      for (int j = 0; j < 4; j++) {
        int row = wn + j*16 + rl;
        bfr[j] = *(const bf16x8*)&lB[(size_t)(row*8 + ((kh*4 + q) ^ (row & 7)))*8];
      }
      #pragma unroll
      for (int i = 0; i < 4; i++)
        #pragma unroll
        for (int j = 0; j < 4; j++)
          acc[i][j] = __builtin_amdgcn_mfma_f32_16x16x32_bf16(af[i], bfr[j], acc[i][j], 0, 0, 0);
    }
  }
}

// ---------------- weight fp32 -> bf16 converters ----------------
__global__ __launch_bounds__(256) void convert_win_kernel(const float* __restrict__ W,
                                                          ushort* __restrict__ Wb)
{
  size_t i = (size_t)blockIdx.x*256 + threadIdx.x;
  Wb[i] = (i < (size_t)DINPROJ*DMODEL) ? f2b(W[i]) : (ushort)0;
}

__global__ __launch_bounds__(256) void convert_wout_kernel(const float* __restrict__ W,
                                                           ushort* __restrict__ Wb)
{
  size_t i = (size_t)blockIdx.x*256 + threadIdx.x;
  Wb[i] = f2b(W[i]);
}

// ---------------- LayerNorm -> h (bf16) ----------------
__global__ __launch_bounds__(256) void ln_kernel(const float* __restrict__ x,
    const float* __restrict__ w, const float* __restrict__ bias, ushort* __restrict__ h)
{
  const int row = blockIdx.x;
  const int t = threadIdx.x;
  const float* xr = x + (size_t)row * DMODEL;
  float v[4];
  float s = 0.f;
  #pragma unroll
  for (int i = 0; i < 4; i++) { v[i] = xr[t + i*256]; s += v[i]; }
  __shared__ float red[4];
  #pragma unroll
  for (int o = 32; o > 0; o >>= 1) s += __shfl_down(s, o, 64);
  if ((t & 63) == 0) red[t >> 6] = s;
  __syncthreads();
  float mean = (red[0]+red[1]+red[2]+red[3]) * (1.f/DMODEL);
  float vs = 0.f;
  #pragma unroll
  for (int i = 0; i < 4; i++) { float d = v[i]-mean; vs += d*d; }
  #pragma unroll
  for (int o = 32; o > 0; o >>= 1) vs += __shfl_down(vs, o, 64);
  __syncthreads();
  if ((t & 63) == 0) red[t >> 6] = vs;
  __syncthreads();
  float rstd = rsqrtf((red[0]+red[1]+red[2]+red[3]) * (1.f/DMODEL) + 1e-5f);
  ushort* hr = h + (size_t)row * DMODEL;
  #pragma unroll
  for (int i = 0; i < 4; i++) {
    int c = t + i*256;
    hr[c] = f2b((v[i]-mean)*rstd*w[c] + bias[c]);
  }
}

// ---------------- in_proj GEMM: 256x128, dbuf prefetch (round-1) + XCD m-partition ----------------
// grid 1120 (1-D): xcd = bid&7 owns m-blocks [4*xcd, 4*xcd+4), n-fastest within (140 = 4x35).
__global__ __launch_bounds__(512, 1) void gemm_inproj_v6(const ushort* __restrict__ A,
    const ushort* __restrict__ W, ushort* __restrict__ z, ushort* __restrict__ xbc,
    float* __restrict__ dtr, const float* __restrict__ dtb)
{
  __shared__ ushort smem[49152];            // 96KB
  ushort* lA0 = smem;                       // 2 x 16384 ushorts
  ushort* lB0 = smem + 32768;               // 2 x 8192  ushorts
  const int tid = threadIdx.x;
  const int lane = tid & 63;
  const int w = tid >> 6;
  const int wr = w >> 1;                    // 0..3 (M)
  const int wc = w & 1;                     // 0..1 (N)
  const int rl = lane & 15;
  const int q  = lane >> 4;

  const int orig = blockIdx.x;              // [0,1120)
  const int xcd  = orig & 7;
  const int jj   = orig >> 3;               // [0,140)
  const int m0 = (xcd*4 + jj/35) * 256;     // A panel pinned per XCD
  const int n0 = (jj % 35) * 128;           // n-fastest

  f32x4 acc[4][4];
  #pragma unroll
  for (int i = 0; i < 4; i++)
    #pragma unroll
    for (int j = 0; j < 4; j++) acc[i][j] = (f32x4)(0.f);

  constexpr int NT = DMODEL / 64;           // 16 K-tiles
  stage_tile<DMODEL>(A, W, m0, n0, tid, 0, lA0, lB0);
  __syncthreads();
  for (int t = 0; t < NT; t++) {
    ushort* cA = lA0 + (size_t)(t & 1) * 16384;
    ushort* cB = lB0 + (size_t)(t & 1) * 8192;
    if (t + 1 < NT)
      stage_tile<DMODEL>(A, W, m0, n0, tid, t + 1,
                         lA0 + (size_t)((t+1) & 1) * 16384,
                         lB0 + (size_t)((t+1) & 1) * 8192);
    __builtin_amdgcn_s_setprio(1);
    compute_tile(cA, cB, wr, wc, rl, q, acc);
    __builtin_amdgcn_s_setprio(0);
    __syncthreads();                        // drains vmcnt (loads had full compute to land)
  }

  const int colL = lane & 15;
  const int rowQ = (lane >> 4) * 4;
  if (n0 < DINNER + CONVCH) {
    // swizzled bf16 restage of the 256x128 tile (64KB), then coalesced 16B stores
    #pragma unroll
    for (int i = 0; i < 4; i++)
      #pragma unroll
      for (int j = 0; j < 4; j++) {
        int col = wc*64 + j*16 + colL;
        int g = col >> 3;
        #pragma unroll
        for (int r = 0; r < 4; r++) {
          int row = wr*64 + i*16 + rowQ + r;
          smem[row*128 + ((g ^ (row & 7)) << 3) + (col & 7)] = f2b(acc[i][j][r]);
        }
      }
    __syncthreads();
    ushort* outp; int coff, ncols;
    if (n0 < DINNER) { outp = z;   coff = n0;          ncols = DINNER; }
    else             { outp = xbc; coff = n0 - DINNER; ncols = CONVCH; }
    #pragma unroll
    for (int it = 0; it < 8; it++) {
      int idx = tid + it*512;               // 256 rows x 16 granules = 4096
      int row = idx >> 4, c8 = idx & 15;
      *(uint4*)(outp + (size_t)(m0 + row)*ncols + coff + c8*8) =
          *(const uint4*)&smem[row*128 + ((c8 ^ (row & 7)) << 3)];
    }
  } else {
    // dt tile (n0 == 4352): only local cols [0,32) real; fused softplus(v + bias)
    if (wc == 0) {
      #pragma unroll
      for (int i = 0; i < 4; i++)
        #pragma unroll
        for (int j = 0; j < 2; j++) {
          int lc = j*16 + colL;             // < 32
          float bb = dtb[lc];
          #pragma unroll
          for (int r = 0; r < 4; r++) {
            float v = acc[i][j][r] + bb;
            v = (v > 20.f) ? v : log1pf(expf(v));
            dtr[(size_t)(m0 + wr*64 + i*16 + rowQ + r)*NHEADS + lc] = v;
          }
        }
    }
  }
}

// ---------------- out_proj GEMM: 128x128 multi-block (round-0) + XCD partition ----------------
// grid 512 (1-D): xcd = bid&7 owns m-blocks [8*xcd, 8*xcd+8), n-fastest within (64 = 8x8).
__global__ __launch_bounds__(256) void gemm_outproj_mfma(const ushort* __restrict__ A,
    const ushort* __restrict__ W, const float* __restrict__ x, float* __restrict__ out)
{
  __shared__ ushort smem[16384];            // 32 KB: staging OR 64x128 fp32 restage
  ushort* lA = smem;
  ushort* lB = smem + 8192;
  float* fbuf = (float*)smem;
  const int tid = threadIdx.x;
  const int lane = tid & 63;
  const int w = tid >> 6;

  const int orig = blockIdx.x;              // [0,512)
  const int xcd  = orig & 7;
  const int jj   = orig >> 3;               // [0,64)
  const int m0 = (xcd*8 + (jj >> 3)) * 128;
  const int n0 = (jj & 7) * 128;

  const int wn = (w >> 1) * 64;
  f32x4 acc[4][4];
  #pragma unroll
  for (int i = 0; i < 4; i++)
    #pragma unroll
    for (int j = 0; j < 4; j++) acc[i][j] = (f32x4)(0.f);

  gemm_core_swz<DINNER>(A, W, m0, n0, tid, lA, lB, acc);

  const int colL = lane & 15;
  const int rowQ = (lane >> 4) * 4;
  #pragma unroll
  for (int h0 = 0; h0 < 2; h0++) {
    __syncthreads();
    if ((w & 1) == h0) {
      #pragma unroll
      for (int i = 0; i < 4; i++)
        #pragma unroll
        for (int j = 0; j < 4; j++) {
          int col = wn + j*16 + colL;
          int g = col >> 2;
          #pragma unroll
          for (int r = 0; r < 4; r++) {
            int row = i*16 + rowQ + r;
            fbuf[row*128 + ((g ^ (row & 7)) << 2) + (col & 3)] = acc[i][j][r];
          }
        }
    }
    __syncthreads();
    #pragma unroll
    for (int it = 0; it < 8; it++) {
      int idx = tid + it*256;
      int row = idx >> 5, c4 = idx & 31;
      int gm = m0 + h0*64 + row;
      float4 xv = *(const float4*)(x + (size_t)gm*DMODEL + n0 + c4*4);
      float4 vv = *(const float4*)&fbuf[row*128 + ((c4 ^ (row & 7)) << 2)];
      vv.x += xv.x; vv.y += xv.y; vv.z += xv.z; vv.w += xv.w;
      *(float4*)(out + (size_t)gm*DMODEL + n0 + c4*4) = vv;
    }
  }
}

// ---------------- causal conv4 + SiLU, LDS row-tiled ----------------
__global__ __launch_bounds__(256) void conv_tiled(const ushort* __restrict__ xbc,
    const float* __restrict__ cw, const float* __restrict__ cb,
    ushort* __restrict__ xs, ushort* __restrict__ bcb)
{
  __shared__ ushort tile[35*256];
  const int tid = threadIdx.x;
  const int ch0 = blockIdx.x * 256;
  const int row0 = blockIdx.y * 32;
  const int l0 = row0 & (LSEQ-1);
  for (int idx = tid; idx < 35*32; idx += 256) {
    int r = idx >> 5, c16 = idx & 31;
    uint4 v = make_uint4(0,0,0,0);
    if (l0 + r - 3 >= 0)
      v = *(const uint4*)(xbc + (size_t)(row0 + r - 3)*CONVCH + ch0 + c16*8);
    *(uint4*)&tile[r*256 + c16*8] = v;
  }
  __syncthreads();
  const int ch = ch0 + tid;
  const float w0 = cw[ch*4+0], w1 = cw[ch*4+1], w2 = cw[ch*4+2], w3 = cw[ch*4+3];
  const float bias = cb[ch];
  const bool isX = (ch0 < DINNER);
  #pragma unroll 4
  for (int r = 0; r < 32; r++) {
    float acc = bias;
    acc = fmaf(b2f(tile[(r+0)*256 + tid]), w0, acc);
    acc = fmaf(b2f(tile[(r+1)*256 + tid]), w1, acc);
    acc = fmaf(b2f(tile[(r+2)*256 + tid]), w2, acc);
    acc = fmaf(b2f(tile[(r+3)*256 + tid]), w3, acc);
    float v = acc / (1.f + expf(-acc));
    if (isX) xs[(size_t)(row0 + r)*DINNER + ch] = f2b(v);
    else     bcb[(size_t)(row0 + r)*256 + (ch - DINNER)] = f2b(v);
  }
}

// ---------------- per-chunk states via MFMA: S[p][n] = sum_l Xw[l][p]*B[l][n] ----------------
__global__ __launch_bounds__(256) void states_mfma(
    const ushort* __restrict__ xs, const ushort* __restrict__ bcb, const float* __restrict__ dt,
    const float* __restrict__ A_log, ushort* __restrict__ S, float* __restrict__ asum)
{
  constexpr int LDP = 136;
  __shared__ ushort lBT[128*LDP];   // B^T[n][l]
  __shared__ ushort lXT[64*LDP];    // Xw^T[p][l]; reused for S restage
  __shared__ float dts[CHUNKL], acs[CHUNKL];
  __shared__ float wtot;
  const int hh = blockIdx.x, c = blockIdx.y, b = blockIdx.z;
  const int tid = threadIdx.x;
  const int lane = tid & 63;
  const int w = tid >> 6;
  const int rbase = b*LSEQ + c*CHUNKL;
  const size_t sbase = (size_t)((b*NCHUNK + c)*NHEADS + hh) * 8192;

  float pre = 0.f;
  if (tid < 128) {
    float myv = dt[(size_t)(rbase + tid)*NHEADS + hh];
    dts[tid] = myv;
    pre = myv;
    #pragma unroll
    for (int o = 1; o < 64; o <<= 1) {
      float u = __shfl_up(pre, o, 64);
      if ((tid & 63) >= o) pre += u;
    }
    if (tid == 63) wtot = pre;
  }
  #pragma unroll
  for (int it = 0; it < 8; it++) {
    int chunk = tid + it*256;
    int l = chunk >> 4, n8 = chunk & 15;
    ushort tmp[8];
    *(uint4*)tmp = *(const uint4*)(bcb + (size_t)(rbase + l)*256 + n8*8);
    #pragma unroll
    for (int u = 0; u < 8; u++) lBT[(n8*8+u)*LDP + l] = tmp[u];
  }
  __syncthreads();
  float alast_loc = 0.f;
  if (tid < 128) {
    float Aval = -expf(A_log[hh]);
    float a = (pre + ((tid >= 64) ? wtot : 0.f)) * Aval;
    acs[tid] = a;
    if (tid == 127) { asum[(b*NCHUNK + c)*NHEADS + hh] = a; }
  }
  __syncthreads();
  alast_loc = acs[CHUNKL-1];
  #pragma unroll
  for (int it = 0; it < 4; it++) {
    int chunk = tid + it*256;
    int l = chunk >> 3, p8 = (chunk & 7)*8;
    ushort tmp[8];
    *(uint4*)tmp = *(const uint4*)(xs + (size_t)(rbase + l)*DINNER + hh*HEADDIM + p8);
    float wl = dts[l] * expf(alast_loc - acs[l]);
    #pragma unroll
    for (int u = 0; u < 8; u++) lXT[(p8+u)*LDP + l] = f2b(b2f(tmp[u]) * wl);
  }
  __syncthreads();

  const int rl = lane & 15;
  const int kq = (lane >> 4) * 8;
  const int nb = w * 32;
  f32x4 acc[4][2];
  #pragma unroll
  for (int i = 0; i < 4; i++) { acc[i][0] = (f32x4)(0.f); acc[i][1] = (f32x4)(0.f); }
  #pragma unroll
  for (int k0 = 0; k0 < 128; k0 += 32) {
    bf16x8 af[4], bfr[2];
    #pragma unroll
    for (int i = 0; i < 4; i++) af[i]  = *(const bf16x8*)&lXT[(i*16 + rl)*LDP + k0 + kq];
    #pragma unroll
    for (int j = 0; j < 2; j++) bfr[j] = *(const bf16x8*)&lBT[(nb + j*16 + rl)*LDP + k0 + kq];
    #pragma unroll
    for (int i = 0; i < 4; i++)
      #pragma unroll
      for (int j = 0; j < 2; j++)
        acc[i][j] = __builtin_amdgcn_mfma_f32_16x16x32_bf16(af[i], bfr[j], acc[i][j], 0, 0, 0);
  }
  __syncthreads();
  const int colL = lane & 15;
  const int rowQ = (lane >> 4) * 4;
  #pragma unroll
  for (int i = 0; i < 4; i++)
    #pragma unroll
    for (int j = 0; j < 2; j++)
      #pragma unroll
      for (int r = 0; r < 4; r++)
        lXT[(i*16 + rowQ + r)*LDP + nb + j*16 + colL] = f2b(acc[i][j][r]);
  __syncthreads();
  #pragma unroll
  for (int it = 0; it < 4; it++) {
    int idx = tid + it*256;
    int row = idx >> 4, c8 = idx & 15;
    *(uint4*)(S + sbase + row*128 + c8*8) = *(const uint4*)&lXT[row*LDP + c8*8];
  }
}

// ---------------- inter-chunk scan, split 4x over state slices ----------------
__global__ __launch_bounds__(256) void scan_kernel(ushort* __restrict__ S, const float* __restrict__ asum)
{
  const int hh = blockIdx.x, sl = blockIdx.y, b = blockIdx.z;
  const int base0 = sl*2048 + threadIdx.x;
  float carry[8];
  #pragma unroll
  for (int i = 0; i < 8; i++) carry[i] = 0.f;
  for (int c = 0; c < NCHUNK; c++) {
    ushort* Sp = S + (size_t)((b*NCHUNK + c)*NHEADS + hh) * 8192;
    float dec = expf(asum[(b*NCHUNK + c)*NHEADS + hh]);
    #pragma unroll
    for (int i = 0; i < 8; i++) {
      int idx = base0 + i*256;
      float sv = b2f(Sp[idx]);
      Sp[idx] = f2b(carry[i]);
      carry[i] = fmaf(dec, carry[i], sv);
    }
  }
}

// ---------------- yssd MFMA v2: direct-global fragments for C/B/P; LDS only M + X^T ----------------
__global__ __launch_bounds__(256) void yssd_mfma(
    const ushort* __restrict__ xs, const ushort* __restrict__ bcb, const float* __restrict__ dt,
    const float* __restrict__ A_log, const float* __restrict__ Dvec,
    const ushort* __restrict__ S, ushort* __restrict__ y)
{
  constexpr int LDP = 136;
  __shared__ ushort lM [128*LDP];   // M[l][s]
  __shared__ ushort lXT[64*LDP];    // X^T[p][s]
  __shared__ float dts[CHUNKL], acs[CHUNKL];
  __shared__ float wtot;
  const int hh = blockIdx.x, c = blockIdx.y, b = blockIdx.z;
  const int tid = threadIdx.x;
  const int lane = tid & 63;
  const int w = tid >> 6;
  const int rbase = b*LSEQ + c*CHUNKL;
  const size_t sbase = (size_t)((b*NCHUNK + c)*NHEADS + hh) * 8192;
  const ushort* Bg = bcb + (size_t)rbase*256;        // B row s at Bg + s*256
  const ushort* Cg = Bg + 128;                       // C row l at Cg + l*256

  // stage X^T (transposing scatter) — the only global->LDS staging
  #pragma unroll
  for (int it = 0; it < 4; it++) {
    int chunk = tid + it*256;
    int s = chunk >> 3, p0 = (chunk & 7)*8;
    ushort tmp[8];
    *(uint4*)tmp = *(const uint4*)(xs + (size_t)(rbase + s)*DINNER + hh*HEADDIM + p0);
    #pragma unroll
    for (int u = 0; u < 8; u++) lXT[(p0+u)*LDP + s] = tmp[u];
  }
  // dt load + wave-parallel inclusive scan
  float pre = 0.f;
  if (tid < 128) {
    float myv = dt[(size_t)(rbase + tid)*NHEADS + hh];
    dts[tid] = myv;
    pre = myv;
    #pragma unroll
    for (int o = 1; o < 64; o <<= 1) {
      float u = __shfl_up(pre, o, 64);
      if ((tid & 63) >= o) pre += u;
    }
    if (tid == 63) wtot = pre;
  }
  __syncthreads();
  if (tid < 128) {
    float Aval = -expf(A_log[hh]);
    acs[tid] = (pre + ((tid >= 64) ? wtot : 0.f)) * Aval;
  }

  const int rl = lane & 15;
  const int kq = (lane >> 4) * 8;
  const int colL = lane & 15;
  const int rowQ = (lane >> 4) * 4;

  // ---- GEMM1: G[l][s] = sum_n C[l][n]*B[s][n], fragments direct from global
  const int wm = (w & 1) * 64;
  const int wn = (w >> 1) * 64;
  f32x4 G[4][4];
  #pragma unroll
  for (int i = 0; i < 4; i++)
    #pragma unroll
    for (int j = 0; j < 4; j++) G[i][j] = (f32x4)(0.f);
  #pragma unroll
  for (int k0 = 0; k0 < 128; k0 += 32) {
    bf16x8 af[4], bfr[4];
    #pragma unroll
    for (int i = 0; i < 4; i++) af[i]  = *(const bf16x8*)(Cg + (size_t)(wm + i*16 + rl)*256 + k0 + kq);
    #pragma unroll
    for (int j = 0; j < 4; j++) bfr[j] = *(const bf16x8*)(Bg + (size_t)(wn + j*16 + rl)*256 + k0 + kq);
    #pragma unroll
    for (int i = 0; i < 4; i++)
      #pragma unroll
      for (int j = 0; j < 4; j++)
        G[i][j] = __builtin_amdgcn_mfma_f32_16x16x32_bf16(af[i], bfr[j], G[i][j], 0, 0, 0);
  }
  __syncthreads();   // acs (written pre-GEMM1 by tid<128) visible to all; XT staged

  // ---- M[l][s] = (l>=s) ? G*exp(acs[l]-acs[s])*dt[s] : 0  -> lM
  #pragma unroll
  for (int j = 0; j < 4; j++) {
    int sIdx = wn + j*16 + colL;
    float as = acs[sIdx];
    float ds = dts[sIdx];
    #pragma unroll
    for (int i = 0; i < 4; i++) {
      #pragma unroll
      for (int r = 0; r < 4; r++) {
        int lIdx = wm + i*16 + rowQ + r;
        float m = (lIdx >= sIdx) ? G[i][j][r] * expf(acs[lIdx] - as) * ds : 0.f;
        lM[lIdx*LDP + sIdx] = f2b(m);
      }
    }
  }

  // ---- GEMM-off: Y[l][p] = sum_n C[l][n]*P[p][n], C and P direct from global
  const int om = w * 32;
  f32x4 Y[2][4];
  #pragma unroll
  for (int i = 0; i < 2; i++)
    #pragma unroll
    for (int j = 0; j < 4; j++) Y[i][j] = (f32x4)(0.f);
  #pragma unroll
  for (int k0 = 0; k0 < 128; k0 += 32) {
    bf16x8 a2[2], b2[4];
    #pragma unroll
    for (int i = 0; i < 2; i++) a2[i] = *(const bf16x8*)(Cg + (size_t)(om + i*16 + rl)*256 + k0 + kq);
    #pragma unroll
    for (int j = 0; j < 4; j++) b2[j] = *(const bf16x8*)(S + sbase + (size_t)(j*16 + rl)*128 + k0 + kq);
    #pragma unroll
    for (int i = 0; i < 2; i++)
      #pragma unroll
      for (int j = 0; j < 4; j++)
        Y[i][j] = __builtin_amdgcn_mfma_f32_16x16x32_bf16(a2[i], b2[j], Y[i][j], 0, 0, 0);
  }
  #pragma unroll
  for (int i = 0; i < 2; i++)
    #pragma unroll
    for (int r = 0; r < 4; r++) {
      float e = expf(acs[om + i*16 + rowQ + r]);
      #pragma unroll
      for (int j = 0; j < 4; j++) Y[i][j][r] *= e;
    }
  __syncthreads();   // lM writes visible

  // ---- GEMM-diag: Y[l][p] += sum_s M[l][s]*XT[p][s]
  #pragma unroll
  for (int k0 = 0; k0 < 128; k0 += 32) {
    bf16x8 a3[2], b3[4];
    #pragma unroll
    for (int i = 0; i < 2; i++) a3[i] = *(const bf16x8*)&lM[(om + i*16 + rl)*LDP + k0 + kq];
    #pragma unroll
    for (int j = 0; j < 4; j++) b3[j] = *(const bf16x8*)&lXT[(j*16 + rl)*LDP + k0 + kq];
    #pragma unroll
    for (int i = 0; i < 2; i++)
      #pragma unroll
      for (int j = 0; j < 4; j++)
        Y[i][j] = __builtin_amdgcn_mfma_f32_16x16x32_bf16(a3[i], b3[j], Y[i][j], 0, 0, 0);
  }

  // ---- epilogue: += D*xs, write bf16
  const float Dh = Dvec[hh];
  #pragma unroll
  for (int i = 0; i < 2; i++) {
    #pragma unroll
    for (int r = 0; r < 4; r++) {
      int lIdx = om + i*16 + rowQ + r;
      ushort* yrow = y + (size_t)(rbase + lIdx)*DINNER + hh*HEADDIM;
      #pragma unroll
      for (int j = 0; j < 4; j++) {
        int p = j*16 + colL;
        float val = Y[i][j][r] + Dh * b2f(lXT[p*LDP + lIdx]);
        yrow[p] = f2b(val);
      }
    }
  }
}

// ---------------- gated RMSNorm (in place on y, bf16) ----------------
__global__ __launch_bounds__(256) void rmsnorm_kernel(ushort* __restrict__ y,
    const ushort* __restrict__ z, const float* __restrict__ nw)
{
  const int row = blockIdx.x;
  const int t = threadIdx.x;
  ushort* yr = y + (size_t)row*DINNER;
  const ushort* zr = z + (size_t)row*DINNER;
  float v[8];
  float ss = 0.f;
  #pragma unroll
  for (int i = 0; i < 8; i++) {
    int c = t + i*256;
    float zz = b2f(zr[c]);
    float g = b2f(yr[c]) * (zz / (1.f + expf(-zz)));
    v[i] = g;
    ss += g*g;
  }
  #pragma unroll
  for (int o = 32; o > 0; o >>= 1) ss += __shfl_down(ss, o, 64);
  __shared__ float red[4];
  if ((t & 63) == 0) red[t >> 6] = ss;
  __syncthreads();
  float scale = rsqrtf((red[0]+red[1]+red[2]+red[3]) * (1.f/DINNER) + 1e-5f);
  #pragma unroll
  for (int i = 0; i < 8; i++) {
    int c = t + i*256;
    yr[c] = f2b(v[i]*scale*nw[c]);
  }
}

extern "C" void kernel_launch(void* const* d_in, const int* in_sizes, int n_in,
                              void* d_out, int out_size, void* d_ws, size_t ws_size,
                              hipStream_t stream)
{
  const float* x    = (const float*)d_in[0];
  const float* lnw  = (const float*)d_in[1];
  const float* lnb  = (const float*)d_in[2];
  const float* win  = (const float*)d_in[3];
  const float* cw   = (const float*)d_in[4];
  const float* cb   = (const float*)d_in[5];
  const float* dtb  = (const float*)d_in[6];
  const float* alog = (const float*)d_in[7];
  const float* dvec = (const float*)d_in[8];
  const float* nw   = (const float*)d_in[9];
  const float* wout = (const float*)d_in[10];
  float* out = (float*)d_out;
  char* ws = (char*)d_ws;
  (void)in_sizes; (void)n_in; (void)out_size;

  if (ws_size < B_END) return;  // workspace too small: fail cleanly, don't fault

  ushort* zb   = (ushort*)(ws + B_Z);
  ushort* xbcb = (ushort*)(ws + B_XBC);
  float*  dtr  = (float*) (ws + B_DT);
  ushort* xsb  = (ushort*)(ws + B_XS);
  ushort* bcb  = (ushort*)(ws + B_BC);
  ushort* yb   = (ushort*)(ws + B_Y);
  float*  asum = (float*) (ws + B_ASUM);
  ushort* Sb   = xbcb;                                        // aliases xbc (dead after conv)
  ushort* hb   = yb;                                          // aliases y[0 : 16.8MB]
  ushort* winB = (ushort*)(ws + B_Y + (size_t)ROWS*DMODEL*2); // aliases y[16.8MB : 26.2MB) (4608x1024 bf16 = 9.44MB)
  ushort* woutB= (ushort*)(ws + B_XBC + (size_t)BATCH*NCHUNK*NHEADS*HEADDIM*DSTATE*2); // XBC tail (4.19MB)

  hipLaunchKernelGGL(convert_win_kernel, dim3((NPAD*DMODEL)/256), dim3(256), 0, stream, win, winB);
  hipLaunchKernelGGL(ln_kernel, dim3(ROWS), dim3(256), 0, stream, x, lnw, lnb, hb);
  hipLaunchKernelGGL(gemm_inproj_v6, dim3(1120), dim3(512), 0, stream, hb, winB, zb, xbcb, dtr, dtb);
  hipLaunchKernelGGL(conv_tiled, dim3(9, ROWS/32), dim3(256), 0, stream, xbcb, cw, cb, xsb, bcb);
  hipLaunchKernelGGL(convert_wout_kernel, dim3((DMODEL*DINNER)/256), dim3(256), 0, stream, wout, woutB);
  hipLaunchKernelGGL(states_mfma, dim3(NHEADS, NCHUNK, BATCH), dim3(256), 0, stream,
                     xsb, bcb, dtr, alog, Sb, asum);
  hipLaunchKernelGGL(scan_kernel, dim3(NHEADS, 4, BATCH), dim3(256), 0, stream, Sb, asum);
  hipLaunchKernelGGL(yssd_mfma, dim3(NHEADS, NCHUNK, BATCH), dim3(256), 0, stream,
                     xsb, bcb, dtr, alog, dvec, Sb, yb);
  hipLaunchKernelGGL(rmsnorm_kernel, dim3(ROWS), dim3(256), 0, stream, yb, zb, nw);
  hipLaunchKernelGGL(gemm_outproj_mfma, dim3(512), dim3(256), 0, stream, yb, woutB, x, out);
}

// Round 7
// 457.686 us; speedup vs baseline: 1.0404x; 1.0082x over previous
//
#include <hip/hip_runtime.h>
#include <math.h>

#define BATCH   4
#define LSEQ    2048
#define DMODEL  1024
#define DSTATE  128
#define HEADDIM 64
#define DINNER  2048
#define NHEADS  32
#define CONVCH  2304
#define DINPROJ 4384
#define NPAD    4608
#define CHUNKL  128
#define NCHUNK  16
#define ROWS    (BATCH*LSEQ)

// ---------------- workspace layout (BYTE offsets) ----------------
#define B_Z     ((size_t)0)                              // ROWS*DINNER bf16
#define B_XBC   (B_Z   + (size_t)ROWS*DINNER*2)          // ROWS*CONVCH bf16; S aliases first 33.55MB; Wout bf16 aliases tail 4.19MB
#define B_DT    (B_XBC + (size_t)ROWS*CONVCH*2)          // ROWS*NHEADS fp32
#define B_XS    (B_DT  + (size_t)ROWS*NHEADS*4)          // ROWS*DINNER bf16
#define B_BC    (B_XS  + (size_t)ROWS*DINNER*2)          // ROWS*256 bf16
#define B_Y     (B_BC  + (size_t)ROWS*256*2)             // ROWS*DINNER bf16; h bf16 aliases [0,16.8MB); Win bf16 aliases [16.8MB,26.2MB)
#define B_ASUM  (B_Y   + (size_t)ROWS*DINNER*2)          // BATCH*NCHUNK*NHEADS fp32
#define B_END   (B_ASUM + (size_t)BATCH*NCHUNK*NHEADS*4) // ~137 MB total

typedef __attribute__((ext_vector_type(8))) short bf16x8;
typedef __attribute__((ext_vector_type(4))) float f32x4;

__device__ __forceinline__ float b2f(ushort u) {
  union { uint32_t i; float f; } v; v.i = ((uint32_t)u) << 16; return v.f;
}
__device__ __forceinline__ ushort f2b(float f) {
  union { float f; uint32_t i; } v; v.f = f;
  uint32_t r = (v.i + 0x7FFFu + ((v.i >> 16) & 1u)) >> 16;
  return (ushort)r;
}

__device__ __forceinline__ void async_ld16(const void* g, void* l) {
  __builtin_amdgcn_global_load_lds(
      (const __attribute__((address_space(1))) unsigned int*)g,
      (__attribute__((address_space(3))) unsigned int*)l, 16, 0, 0);
}

// ================= 256x128 inproj helpers (round-6 measured-best) =================
template<int K>
__device__ __forceinline__ void stage_tile(const ushort* __restrict__ A,
    const ushort* __restrict__ W, int m0, int n0, int tid, int t,
    ushort* lA, ushort* lB)
{
  const int k0 = t * 64;
  #pragma unroll
  for (int it = 0; it < 4; it++) {          // A: 256 rows x 8 granules = 2048 slots
    int s = it*512 + tid;
    int row = s >> 3;
    int g = (s & 7) ^ (row & 7);
    async_ld16(A + (size_t)(m0 + row)*K + k0 + g*8, lA + (size_t)s*8);
  }
  #pragma unroll
  for (int it = 0; it < 2; it++) {          // B: 128 rows x 8 granules = 1024 slots
    int s = it*512 + tid;
    int row = s >> 3;
    int g = (s & 7) ^ (row & 7);
    async_ld16(W + (size_t)(n0 + row)*K + k0 + g*8, lB + (size_t)s*8);
  }
}

__device__ __forceinline__ void compute_tile(const ushort* lA, const ushort* lB,
    int wr, int wc, int rl, int q, f32x4 acc[4][4])
{
  #pragma unroll
  for (int kh = 0; kh < 2; kh++) {
    bf16x8 af[4], bfr[4];
    #pragma unroll
    for (int i = 0; i < 4; i++) {
      int row = wr*64 + i*16 + rl;
      af[i] = *(const bf16x8*)&lA[(size_t)(row*8 + ((kh*4 + q) ^ (row & 7)))*8];
    }
    #pragma unroll
    for (int j = 0; j < 4; j++) {
      int row = wc*64 + j*16 + rl;
      bfr[j] = *(const bf16x8*)&lB[(size_t)(row*8 + ((kh*4 + q) ^ (row & 7)))*8];
    }
    #pragma unroll
    for (int i = 0; i < 4; i++)
      #pragma unroll
      for (int j = 0; j < 4; j++)
        acc[i][j] = __builtin_amdgcn_mfma_f32_16x16x32_bf16(af[i], bfr[j], acc[i][j], 0, 0, 0);
  }
}

// ================= 128x128 shared core (round-0, multi-block/CU) =================
template<int K>
__device__ __forceinline__ void gemm_core_swz(const ushort* __restrict__ A,
    const ushort* __restrict__ W, int m0, int n0, int tid,
    ushort* lA, ushort* lB, f32x4 acc[4][4])
{
  const int lane = tid & 63;
  const int w = tid >> 6;
  const int wm = (w & 1) * 64;
  const int wn = (w >> 1) * 64;
  const int rl = lane & 15;
  const int q  = lane >> 4;
  for (int k0 = 0; k0 < K; k0 += 64) {
    __syncthreads();
    #pragma unroll
    for (int is = 0; is < 4; is++) {
      int s = (w*4 + is)*64 + lane;
      int row = s >> 3;
      int g = (s & 7) ^ (row & 7);
      async_ld16(A + (size_t)(m0 + row)*K + k0 + g*8, lA + (size_t)s*8);
      async_ld16(W + (size_t)(n0 + row)*K + k0 + g*8, lB + (size_t)s*8);
    }
    __syncthreads();
    #pragma unroll
    for (int kh = 0; kh < 2; kh++) {
      bf16x8 af[4], bfr[4];
      #pragma unroll
      for (int i = 0; i < 4; i++) {
        int row = wm + i*16 + rl;
        af[i] = *(const bf16x8*)&lA[(size_t)(row*8 + ((kh*4 + q) ^ (row & 7)))*8];
      }
      #pragma unroll
      for (int j = 0; j < 4; j++) {
        int row = wn + j*16 + rl;
        bfr[j] = *(const bf16x8*)&lB[(size_t)(row*8 + ((kh*4 + q) ^ (row & 7)))*8];
      }
      #pragma unroll
      for (int i = 0; i < 4; i++)
        #pragma unroll
        for (int j = 0; j < 4; j++)
          acc[i][j] = __builtin_amdgcn_mfma_f32_16x16x32_bf16(af[i], bfr[j], acc[i][j], 0, 0, 0);
    }
  }
}

// ---------------- weight fp32 -> bf16 converters ----------------
__global__ __launch_bounds__(256) void convert_win_kernel(const float* __restrict__ W,
                                                          ushort* __restrict__ Wb)
{
  size_t i = (size_t)blockIdx.x*256 + threadIdx.x;
  Wb[i] = (i < (size_t)DINPROJ*DMODEL) ? f2b(W[i]) : (ushort)0;
}

__global__ __launch_bounds__(256) void convert_wout_kernel(const float* __restrict__ W,
                                                           ushort* __restrict__ Wb)
{
  size_t i = (size_t)blockIdx.x*256 + threadIdx.x;
  Wb[i] = f2b(W[i]);
}

// ---------------- LayerNorm -> h (bf16), float4-vectorized ----------------
__global__ __launch_bounds__(256) void ln_kernel(const float* __restrict__ x,
    const float* __restrict__ w, const float* __restrict__ bias, ushort* __restrict__ h)
{
  const int row = blockIdx.x;
  const int t = threadIdx.x;
  const float* xr = x + (size_t)row * DMODEL;
  float4 xv = *(const float4*)(xr + t*4);
  float s = xv.x + xv.y + xv.z + xv.w;
  __shared__ float red[4];
  #pragma unroll
  for (int o = 32; o > 0; o >>= 1) s += __shfl_down(s, o, 64);
  if ((t & 63) == 0) red[t >> 6] = s;
  __syncthreads();
  float mean = (red[0]+red[1]+red[2]+red[3]) * (1.f/DMODEL);
  float d0 = xv.x-mean, d1 = xv.y-mean, d2 = xv.z-mean, d3 = xv.w-mean;
  float vs = d0*d0 + d1*d1 + d2*d2 + d3*d3;
  #pragma unroll
  for (int o = 32; o > 0; o >>= 1) vs += __shfl_down(vs, o, 64);
  __syncthreads();
  if ((t & 63) == 0) red[t >> 6] = vs;
  __syncthreads();
  float rstd = rsqrtf((red[0]+red[1]+red[2]+red[3]) * (1.f/DMODEL) + 1e-5f);
  float4 wv = *(const float4*)(w + t*4);
  float4 bv = *(const float4*)(bias + t*4);
  ushort4 ov;
  ov.x = f2b(d0*rstd*wv.x + bv.x);
  ov.y = f2b(d1*rstd*wv.y + bv.y);
  ov.z = f2b(d2*rstd*wv.z + bv.z);
  ov.w = f2b(d3*rstd*wv.w + bv.w);
  *(ushort4*)(h + (size_t)row*DMODEL + t*4) = ov;
}

// ---------------- in_proj GEMM: 256x128 dbuf + XCD m-partition (round-6 best) ----------------
// grid 1120 (1-D): xcd = bid&7 owns m-blocks [4*xcd, 4*xcd+4), n-fastest within (140 = 4x35).
__global__ __launch_bounds__(512, 1) void gemm_inproj_v6(const ushort* __restrict__ A,
    const ushort* __restrict__ W, ushort* __restrict__ z, ushort* __restrict__ xbc,
    float* __restrict__ dtr, const float* __restrict__ dtb)
{
  __shared__ ushort smem[49152];            // 96KB
  ushort* lA0 = smem;                       // 2 x 16384 ushorts
  ushort* lB0 = smem + 32768;               // 2 x 8192  ushorts
  const int tid = threadIdx.x;
  const int lane = tid & 63;
  const int w = tid >> 6;
  const int wr = w >> 1;                    // 0..3 (M)
  const int wc = w & 1;                     // 0..1 (N)
  const int rl = lane & 15;
  const int q  = lane >> 4;

  const int orig = blockIdx.x;              // [0,1120)
  const int xcd  = orig & 7;
  const int jj   = orig >> 3;               // [0,140)
  const int m0 = (xcd*4 + jj/35) * 256;     // A panel pinned per XCD
  const int n0 = (jj % 35) * 128;           // n-fastest

  f32x4 acc[4][4];
  #pragma unroll
  for (int i = 0; i < 4; i++)
    #pragma unroll
    for (int j = 0; j < 4; j++) acc[i][j] = (f32x4)(0.f);

  constexpr int NT = DMODEL / 64;           // 16 K-tiles
  stage_tile<DMODEL>(A, W, m0, n0, tid, 0, lA0, lB0);
  __syncthreads();
  for (int t = 0; t < NT; t++) {
    ushort* cA = lA0 + (size_t)(t & 1) * 16384;
    ushort* cB = lB0 + (size_t)(t & 1) * 8192;
    if (t + 1 < NT)
      stage_tile<DMODEL>(A, W, m0, n0, tid, t + 1,
                         lA0 + (size_t)((t+1) & 1) * 16384,
                         lB0 + (size_t)((t+1) & 1) * 8192);
    __builtin_amdgcn_s_setprio(1);
    compute_tile(cA, cB, wr, wc, rl, q, acc);
    __builtin_amdgcn_s_setprio(0);
    __syncthreads();                        // drains vmcnt (loads had full compute to land)
  }

  const int colL = lane & 15;
  const int rowQ = (lane >> 4) * 4;
  if (n0 < DINNER + CONVCH) {
    // swizzled bf16 restage of the 256x128 tile (64KB), then coalesced 16B stores
    #pragma unroll
    for (int i = 0; i < 4; i++)
      #pragma unroll
      for (int j = 0; j < 4; j++) {
        int col = wc*64 + j*16 + colL;
        int g = col >> 3;
        #pragma unroll
        for (int r = 0; r < 4; r++) {
          int row = wr*64 + i*16 + rowQ + r;
          smem[row*128 + ((g ^ (row & 7)) << 3) + (col & 7)] = f2b(acc[i][j][r]);
        }
      }
    __syncthreads();
    ushort* outp; int coff, ncols;
    if (n0 < DINNER) { outp = z;   coff = n0;          ncols = DINNER; }
    else             { outp = xbc; coff = n0 - DINNER; ncols = CONVCH; }
    #pragma unroll
    for (int it = 0; it < 8; it++) {
      int idx = tid + it*512;               // 256 rows x 16 granules = 4096
      int row = idx >> 4, c8 = idx & 15;
      *(uint4*)(outp + (size_t)(m0 + row)*ncols + coff + c8*8) =
          *(const uint4*)&smem[row*128 + ((c8 ^ (row & 7)) << 3)];
    }
  } else {
    // dt tile (n0 == 4352): only local cols [0,32) real; fused softplus(v + bias)
    if (wc == 0) {
      #pragma unroll
      for (int i = 0; i < 4; i++)
        #pragma unroll
        for (int j = 0; j < 2; j++) {
          int lc = j*16 + colL;             // < 32
          float bb = dtb[lc];
          #pragma unroll
          for (int r = 0; r < 4; r++) {
            float v = acc[i][j][r] + bb;
            v = (v > 20.f) ? v : log1pf(expf(v));
            dtr[(size_t)(m0 + wr*64 + i*16 + rowQ + r)*NHEADS + lc] = v;
          }
        }
    }
  }
}

// ---------------- out_proj GEMM: 128x128 multi-block, round-0 2-D grid (reverted) ----------------
__global__ __launch_bounds__(256) void gemm_outproj_mfma(const ushort* __restrict__ A,
    const ushort* __restrict__ W, const float* __restrict__ x, float* __restrict__ out)
{
  __shared__ ushort smem[16384];            // 32 KB: staging OR 64x128 fp32 restage
  ushort* lA = smem;
  ushort* lB = smem + 8192;
  float* fbuf = (float*)smem;
  const int tid = threadIdx.x;
  const int lane = tid & 63;
  const int w = tid >> 6;
  const int m0 = blockIdx.x * 128;
  const int n0 = blockIdx.y * 128;

  const int wn = (w >> 1) * 64;
  f32x4 acc[4][4];
  #pragma unroll
  for (int i = 0; i < 4; i++)
    #pragma unroll
    for (int j = 0; j < 4; j++) acc[i][j] = (f32x4)(0.f);

  gemm_core_swz<DINNER>(A, W, m0, n0, tid, lA, lB, acc);

  const int colL = lane & 15;
  const int rowQ = (lane >> 4) * 4;
  #pragma unroll
  for (int h0 = 0; h0 < 2; h0++) {
    __syncthreads();
    if ((w & 1) == h0) {
      #pragma unroll
      for (int i = 0; i < 4; i++)
        #pragma unroll
        for (int j = 0; j < 4; j++) {
          int col = wn + j*16 + colL;
          int g = col >> 2;
          #pragma unroll
          for (int r = 0; r < 4; r++) {
            int row = i*16 + rowQ + r;
            fbuf[row*128 + ((g ^ (row & 7)) << 2) + (col & 3)] = acc[i][j][r];
          }
        }
    }
    __syncthreads();
    #pragma unroll
    for (int it = 0; it < 8; it++) {
      int idx = tid + it*256;
      int row = idx >> 5, c4 = idx & 31;
      int gm = m0 + h0*64 + row;
      float4 xv = *(const float4*)(x + (size_t)gm*DMODEL + n0 + c4*4);
      float4 vv = *(const float4*)&fbuf[row*128 + ((c4 ^ (row & 7)) << 2)];
      vv.x += xv.x; vv.y += xv.y; vv.z += xv.z; vv.w += xv.w;
      *(float4*)(out + (size_t)gm*DMODEL + n0 + c4*4) = vv;
    }
  }
}

// ---------------- causal conv4 + SiLU, LDS row-tiled ----------------
__global__ __launch_bounds__(256) void conv_tiled(const ushort* __restrict__ xbc,
    const float* __restrict__ cw, const float* __restrict__ cb,
    ushort* __restrict__ xs, ushort* __restrict__ bcb)
{
  __shared__ ushort tile[35*256];
  const int tid = threadIdx.x;
  const int ch0 = blockIdx.x * 256;
  const int row0 = blockIdx.y * 32;
  const int l0 = row0 & (LSEQ-1);
  for (int idx = tid; idx < 35*32; idx += 256) {
    int r = idx >> 5, c16 = idx & 31;
    uint4 v = make_uint4(0,0,0,0);
    if (l0 + r - 3 >= 0)
      v = *(const uint4*)(xbc + (size_t)(row0 + r - 3)*CONVCH + ch0 + c16*8);
    *(uint4*)&tile[r*256 + c16*8] = v;
  }
  __syncthreads();
  const int ch = ch0 + tid;
  const float w0 = cw[ch*4+0], w1 = cw[ch*4+1], w2 = cw[ch*4+2], w3 = cw[ch*4+3];
  const float bias = cb[ch];
  const bool isX = (ch0 < DINNER);
  #pragma unroll 4
  for (int r = 0; r < 32; r++) {
    float acc = bias;
    acc = fmaf(b2f(tile[(r+0)*256 + tid]), w0, acc);
    acc = fmaf(b2f(tile[(r+1)*256 + tid]), w1, acc);
    acc = fmaf(b2f(tile[(r+2)*256 + tid]), w2, acc);
    acc = fmaf(b2f(tile[(r+3)*256 + tid]), w3, acc);
    float v = acc / (1.f + expf(-acc));
    if (isX) xs[(size_t)(row0 + r)*DINNER + ch] = f2b(v);
    else     bcb[(size_t)(row0 + r)*256 + (ch - DINNER)] = f2b(v);
  }
}

// ---------------- per-chunk states via MFMA: S[p][n] = sum_l Xw[l][p]*B[l][n] ----------------
__global__ __launch_bounds__(256) void states_mfma(
    const ushort* __restrict__ xs, const ushort* __restrict__ bcb, const float* __restrict__ dt,
    const float* __restrict__ A_log, ushort* __restrict__ S, float* __restrict__ asum)
{
  constexpr int LDP = 136;
  __shared__ ushort lBT[128*LDP];   // B^T[n][l]
  __shared__ ushort lXT[64*LDP];    // Xw^T[p][l]; reused for S restage
  __shared__ float dts[CHUNKL], acs[CHUNKL];
  __shared__ float wtot;
  const int hh = blockIdx.x, c = blockIdx.y, b = blockIdx.z;
  const int tid = threadIdx.x;
  const int lane = tid & 63;
  const int w = tid >> 6;
  const int rbase = b*LSEQ + c*CHUNKL;
  const size_t sbase = (size_t)((b*NCHUNK + c)*NHEADS + hh) * 8192;

  float pre = 0.f;
  if (tid < 128) {
    float myv = dt[(size_t)(rbase + tid)*NHEADS + hh];
    dts[tid] = myv;
    pre = myv;
    #pragma unroll
    for (int o = 1; o < 64; o <<= 1) {
      float u = __shfl_up(pre, o, 64);
      if ((tid & 63) >= o) pre += u;
    }
    if (tid == 63) wtot = pre;
  }
  #pragma unroll
  for (int it = 0; it < 8; it++) {
    int chunk = tid + it*256;
    int l = chunk >> 4, n8 = chunk & 15;
    ushort tmp[8];
    *(uint4*)tmp = *(const uint4*)(bcb + (size_t)(rbase + l)*256 + n8*8);
    #pragma unroll
    for (int u = 0; u < 8; u++) lBT[(n8*8+u)*LDP + l] = tmp[u];
  }
  __syncthreads();
  float alast_loc = 0.f;
  if (tid < 128) {
    float Aval = -expf(A_log[hh]);
    float a = (pre + ((tid >= 64) ? wtot : 0.f)) * Aval;
    acs[tid] = a;
    if (tid == 127) { asum[(b*NCHUNK + c)*NHEADS + hh] = a; }
  }
  __syncthreads();
  alast_loc = acs[CHUNKL-1];
  #pragma unroll
  for (int it = 0; it < 4; it++) {
    int chunk = tid + it*256;
    int l = chunk >> 3, p8 = (chunk & 7)*8;
    ushort tmp[8];
    *(uint4*)tmp = *(const uint4*)(xs + (size_t)(rbase + l)*DINNER + hh*HEADDIM + p8);
    float wl = dts[l] * expf(alast_loc - acs[l]);
    #pragma unroll
    for (int u = 0; u < 8; u++) lXT[(p8+u)*LDP + l] = f2b(b2f(tmp[u]) * wl);
  }
  __syncthreads();

  const int rl = lane & 15;
  const int kq = (lane >> 4) * 8;
  const int nb = w * 32;
  f32x4 acc[4][2];
  #pragma unroll
  for (int i = 0; i < 4; i++) { acc[i][0] = (f32x4)(0.f); acc[i][1] = (f32x4)(0.f); }
  #pragma unroll
  for (int k0 = 0; k0 < 128; k0 += 32) {
    bf16x8 af[4], bfr[2];
    #pragma unroll
    for (int i = 0; i < 4; i++) af[i]  = *(const bf16x8*)&lXT[(i*16 + rl)*LDP + k0 + kq];
    #pragma unroll
    for (int j = 0; j < 2; j++) bfr[j] = *(const bf16x8*)&lBT[(nb + j*16 + rl)*LDP + k0 + kq];
    #pragma unroll
    for (int i = 0; i < 4; i++)
      #pragma unroll
      for (int j = 0; j < 2; j++)
        acc[i][j] = __builtin_amdgcn_mfma_f32_16x16x32_bf16(af[i], bfr[j], acc[i][j], 0, 0, 0);
  }
  __syncthreads();
  const int colL = lane & 15;
  const int rowQ = (lane >> 4) * 4;
  #pragma unroll
  for (int i = 0; i < 4; i++)
    #pragma unroll
    for (int j = 0; j < 2; j++)
      #pragma unroll
      for (int r = 0; r < 4; r++)
        lXT[(i*16 + rowQ + r)*LDP + nb + j*16 + colL] = f2b(acc[i][j][r]);
  __syncthreads();
  #pragma unroll
  for (int it = 0; it < 4; it++) {
    int idx = tid + it*256;
    int row = idx >> 4, c8 = idx & 15;
    *(uint4*)(S + sbase + row*128 + c8*8) = *(const uint4*)&lXT[row*LDP + c8*8];
  }
}

// ---------------- inter-chunk scan: uint4-vectorized (8 consecutive bf16/thread) ----------------
__global__ __launch_bounds__(256) void scan_kernel(ushort* __restrict__ S, const float* __restrict__ asum)
{
  const int hh = blockIdx.x, sl = blockIdx.y, b = blockIdx.z;
  const int base = sl*2048 + threadIdx.x*8;   // 8 consecutive elements per thread
  float carry[8];
  #pragma unroll
  for (int i = 0; i < 8; i++) carry[i] = 0.f;
  for (int c = 0; c < NCHUNK; c++) {
    ushort* Sp = S + (size_t)((b*NCHUNK + c)*NHEADS + hh) * 8192;
    float dec = expf(asum[(b*NCHUNK + c)*NHEADS + hh]);
    uint4 v = *(const uint4*)(Sp + base);
    ushort* pv = (ushort*)&v;
    uint4 o;
    ushort* po = (ushort*)&o;
    #pragma unroll
    for (int i = 0; i < 8; i++) {
      float sv = b2f(pv[i]);
      po[i] = f2b(carry[i]);
      carry[i] = fmaf(dec, carry[i], sv);
    }
    *(uint4*)(Sp + base) = o;
  }
}

// ---------------- yssd MFMA v2: direct-global fragments for C/B/P; LDS only M + X^T ----------------
__global__ __launch_bounds__(256) void yssd_mfma(
    const ushort* __restrict__ xs, const ushort* __restrict__ bcb, const float* __restrict__ dt,
    const float* __restrict__ A_log, const float* __restrict__ Dvec,
    const ushort* __restrict__ S, ushort* __restrict__ y)
{
  constexpr int LDP = 136;
  __shared__ ushort lM [128*LDP];   // M[l][s]
  __shared__ ushort lXT[64*LDP];    // X^T[p][s]
  __shared__ float dts[CHUNKL], acs[CHUNKL];
  __shared__ float wtot;
  const int hh = blockIdx.x, c = blockIdx.y, b = blockIdx.z;
  const int tid = threadIdx.x;
  const int lane = tid & 63;
  const int w = tid >> 6;
  const int rbase = b*LSEQ + c*CHUNKL;
  const size_t sbase = (size_t)((b*NCHUNK + c)*NHEADS + hh) * 8192;
  const ushort* Bg = bcb + (size_t)rbase*256;        // B row s at Bg + s*256
  const ushort* Cg = Bg + 128;                       // C row l at Cg + l*256

  // stage X^T (transposing scatter) — the only global->LDS staging
  #pragma unroll
  for (int it = 0; it < 4; it++) {
    int chunk = tid + it*256;
    int s = chunk >> 3, p0 = (chunk & 7)*8;
    ushort tmp[8];
    *(uint4*)tmp = *(const uint4*)(xs + (size_t)(rbase + s)*DINNER + hh*HEADDIM + p0);
    #pragma unroll
    for (int u = 0; u < 8; u++) lXT[(p0+u)*LDP + s] = tmp[u];
  }
  // dt load + wave-parallel inclusive scan
  float pre = 0.f;
  if (tid < 128) {
    float myv = dt[(size_t)(rbase + tid)*NHEADS + hh];
    dts[tid] = myv;
    pre = myv;
    #pragma unroll
    for (int o = 1; o < 64; o <<= 1) {
      float u = __shfl_up(pre, o, 64);
      if ((tid & 63) >= o) pre += u;
    }
    if (tid == 63) wtot = pre;
  }
  __syncthreads();
  if (tid < 128) {
    float Aval = -expf(A_log[hh]);
    acs[tid] = (pre + ((tid >= 64) ? wtot : 0.f)) * Aval;
  }

  const int rl = lane & 15;
  const int kq = (lane >> 4) * 8;
  const int colL = lane & 15;
  const int rowQ = (lane >> 4) * 4;

  // ---- GEMM1: G[l][s] = sum_n C[l][n]*B[s][n], fragments direct from global
  const int wm = (w & 1) * 64;
  const int wn = (w >> 1) * 64;
  f32x4 G[4][4];
  #pragma unroll
  for (int i = 0; i < 4; i++)
    #pragma unroll
    for (int j = 0; j < 4; j++) G[i][j] = (f32x4)(0.f);
  #pragma unroll
  for (int k0 = 0; k0 < 128; k0 += 32) {
    bf16x8 af[4], bfr[4];
    #pragma unroll
    for (int i = 0; i < 4; i++) af[i]  = *(const bf16x8*)(Cg + (size_t)(wm + i*16 + rl)*256 + k0 + kq);
    #pragma unroll
    for (int j = 0; j < 4; j++) bfr[j] = *(const bf16x8*)(Bg + (size_t)(wn + j*16 + rl)*256 + k0 + kq);
    #pragma unroll
    for (int i = 0; i < 4; i++)
      #pragma unroll
      for (int j = 0; j < 4; j++)
        G[i][j] = __builtin_amdgcn_mfma_f32_16x16x32_bf16(af[i], bfr[j], G[i][j], 0, 0, 0);
  }
  __syncthreads();   // acs (written pre-GEMM1 by tid<128) visible to all; XT staged

  // ---- M[l][s] = (l>=s) ? G*exp(acs[l]-acs[s])*dt[s] : 0  -> lM
  #pragma unroll
  for (int j = 0; j < 4; j++) {
    int sIdx = wn + j*16 + colL;
    float as = acs[sIdx];
    float ds = dts[sIdx];
    #pragma unroll
    for (int i = 0; i < 4; i++) {
      #pragma unroll
      for (int r = 0; r < 4; r++) {
        int lIdx = wm + i*16 + rowQ + r;
        float m = (lIdx >= sIdx) ? G[i][j][r] * expf(acs[lIdx] - as) * ds : 0.f;
        lM[lIdx*LDP + sIdx] = f2b(m);
      }
    }
  }

  // ---- GEMM-off: Y[l][p] = sum_n C[l][n]*P[p][n], C and P direct from global
  const int om = w * 32;
  f32x4 Y[2][4];
  #pragma unroll
  for (int i = 0; i < 2; i++)
    #pragma unroll
    for (int j = 0; j < 4; j++) Y[i][j] = (f32x4)(0.f);
  #pragma unroll
  for (int k0 = 0; k0 < 128; k0 += 32) {
    bf16x8 a2[2], b2[4];
    #pragma unroll
    for (int i = 0; i < 2; i++) a2[i] = *(const bf16x8*)(Cg + (size_t)(om + i*16 + rl)*256 + k0 + kq);
    #pragma unroll
    for (int j = 0; j < 4; j++) b2[j] = *(const bf16x8*)(S + sbase + (size_t)(j*16 + rl)*128 + k0 + kq);
    #pragma unroll
    for (int i = 0; i < 2; i++)
      #pragma unroll
      for (int j = 0; j < 4; j++)
        Y[i][j] = __builtin_amdgcn_mfma_f32_16x16x32_bf16(a2[i], b2[j], Y[i][j], 0, 0, 0);
  }
  #pragma unroll
  for (int i = 0; i < 2; i++)
    #pragma unroll
    for (int r = 0; r < 4; r++) {
      float e = expf(acs[om + i*16 + rowQ + r]);
      #pragma unroll
      for (int j = 0; j < 4; j++) Y[i][j][r] *= e;
    }
  __syncthreads();   // lM writes visible

  // ---- GEMM-diag: Y[l][p] += sum_s M[l][s]*XT[p][s]
  #pragma unroll
  for (int k0 = 0; k0 < 128; k0 += 32) {
    bf16x8 a3[2], b3[4];
    #pragma unroll
    for (int i = 0; i < 2; i++) a3[i] = *(const bf16x8*)&lM[(om + i*16 + rl)*LDP + k0 + kq];
    #pragma unroll
    for (int j = 0; j < 4; j++) b3[j] = *(const bf16x8*)&lXT[(j*16 + rl)*LDP + k0 + kq];
    #pragma unroll
    for (int i = 0; i < 2; i++)
      #pragma unroll
      for (int j = 0; j < 4; j++)
        Y[i][j] = __builtin_amdgcn_mfma_f32_16x16x32_bf16(a3[i], b3[j], Y[i][j], 0, 0, 0);
  }

  // ---- epilogue: += D*xs, write bf16
  const float Dh = Dvec[hh];
  #pragma unroll
  for (int i = 0; i < 2; i++) {
    #pragma unroll
    for (int r = 0; r < 4; r++) {
      int lIdx = om + i*16 + rowQ + r;
      ushort* yrow = y + (size_t)(rbase + lIdx)*DINNER + hh*HEADDIM;
      #pragma unroll
      for (int j = 0; j < 4; j++) {
        int p = j*16 + colL;
        float val = Y[i][j][r] + Dh * b2f(lXT[p*LDP + lIdx]);
        yrow[p] = f2b(val);
      }
    }
  }
}

// ---------------- gated RMSNorm (in place on y, bf16), uint4-vectorized ----------------
__global__ __launch_bounds__(256) void rmsnorm_kernel(ushort* __restrict__ y,
    const ushort* __restrict__ z, const float* __restrict__ nw)
{
  const int row = blockIdx.x;
  const int t = threadIdx.x;
  ushort* yr = y + (size_t)row*DINNER;
  const ushort* zr = z + (size_t)row*DINNER;
  const int base = t*8;                       // 8 consecutive bf16 per thread
  uint4 yv = *(const uint4*)(yr + base);
  uint4 zv = *(const uint4*)(zr + base);
  const ushort* py = (const ushort*)&yv;
  const ushort* pz = (const ushort*)&zv;
  float v[8];
  float ss = 0.f;
  #pragma unroll
  for (int i = 0; i < 8; i++) {
    float zz = b2f(pz[i]);
    float g = b2f(py[i]) * (zz / (1.f + expf(-zz)));
    v[i] = g;
    ss += g*g;
  }
  #pragma unroll
  for (int o = 32; o > 0; o >>= 1) ss += __shfl_down(ss, o, 64);
  __shared__ float red[4];
  if ((t & 63) == 0) red[t >> 6] = ss;
  __syncthreads();
  float scale = rsqrtf((red[0]+red[1]+red[2]+red[3]) * (1.f/DINNER) + 1e-5f);
  float4 n0 = *(const float4*)(nw + base);
  float4 n1 = *(const float4*)(nw + base + 4);
  uint4 ov;
  ushort* po = (ushort*)&ov;
  po[0] = f2b(v[0]*scale*n0.x); po[1] = f2b(v[1]*scale*n0.y);
  po[2] = f2b(v[2]*scale*n0.z); po[3] = f2b(v[3]*scale*n0.w);
  po[4] = f2b(v[4]*scale*n1.x); po[5] = f2b(v[5]*scale*n1.y);
  po[6] = f2b(v[6]*scale*n1.z); po[7] = f2b(v[7]*scale*n1.w);
  *(uint4*)(yr + base) = ov;
}

extern "C" void kernel_launch(void* const* d_in, const int* in_sizes, int n_in,
                              void* d_out, int out_size, void* d_ws, size_t ws_size,
                              hipStream_t stream)
{
  const float* x    = (const float*)d_in[0];
  const float* lnw  = (const float*)d_in[1];
  const float* lnb  = (const float*)d_in[2];
  const float* win  = (const float*)d_in[3];
  const float* cw   = (const float*)d_in[4];
  const float* cb   = (const float*)d_in[5];
  const float* dtb  = (const float*)d_in[6];
  const float* alog = (const float*)d_in[7];
  const float* dvec = (const float*)d_in[8];
  const float* nw   = (const float*)d_in[9];
  const float* wout = (const float*)d_in[10];
  float* out = (float*)d_out;
  char* ws = (char*)d_ws;
  (void)in_sizes; (void)n_in; (void)out_size;

  if (ws_size < B_END) return;  // workspace too small: fail cleanly, don't fault

  ushort* zb   = (ushort*)(ws + B_Z);
  ushort* xbcb = (ushort*)(ws + B_XBC);
  float*  dtr  = (float*) (ws + B_DT);
  ushort* xsb  = (ushort*)(ws + B_XS);
  ushort* bcb  = (ushort*)(ws + B_BC);
  ushort* yb   = (ushort*)(ws + B_Y);
  float*  asum = (float*) (ws + B_ASUM);
  ushort* Sb   = xbcb;                                        // aliases xbc (dead after conv)
  ushort* hb   = yb;                                          // aliases y[0 : 16.8MB]
  ushort* winB = (ushort*)(ws + B_Y + (size_t)ROWS*DMODEL*2); // aliases y[16.8MB : 26.2MB) (4608x1024 bf16 = 9.44MB)
  ushort* woutB= (ushort*)(ws + B_XBC + (size_t)BATCH*NCHUNK*NHEADS*HEADDIM*DSTATE*2); // XBC tail (4.19MB)

  hipLaunchKernelGGL(convert_win_kernel, dim3((NPAD*DMODEL)/256), dim3(256), 0, stream, win, winB);
  hipLaunchKernelGGL(ln_kernel, dim3(ROWS), dim3(256), 0, stream, x, lnw, lnb, hb);
  hipLaunchKernelGGL(gemm_inproj_v6, dim3(1120), dim3(512), 0, stream, hb, winB, zb, xbcb, dtr, dtb);
  hipLaunchKernelGGL(conv_tiled, dim3(9, ROWS/32), dim3(256), 0, stream, xbcb, cw, cb, xsb, bcb);
  hipLaunchKernelGGL(convert_wout_kernel, dim3((DMODEL*DINNER)/256), dim3(256), 0, stream, wout, woutB);
  hipLaunchKernelGGL(states_mfma, dim3(NHEADS, NCHUNK, BATCH), dim3(256), 0, stream,
                     xsb, bcb, dtr, alog, Sb, asum);
  hipLaunchKernelGGL(scan_kernel, dim3(NHEADS, 4, BATCH), dim3(256), 0, stream, Sb, asum);
  hipLaunchKernelGGL(yssd_mfma, dim3(NHEADS, NCHUNK, BATCH), dim3(256), 0, stream,
                     xsb, bcb, dtr, alog, dvec, Sb, yb);
  hipLaunchKernelGGL(rmsnorm_kernel, dim3(ROWS), dim3(256), 0, stream, yb, zb, nw);
  hipLaunchKernelGGL(gemm_outproj_mfma, dim3(64, 8), dim3(256), 0, stream, yb, woutB, x, out);
}